// Round 9
// baseline (2262.085 us; speedup 1.0000x reference)
//
#include <hip/hip_runtime.h>

// Qwen2.5-VL vision tower forward, MI355X gfx950 — round 8.
// Change vs r7: weight pre-conversion pass removed. GEMMs consume f32 weights
// directly: B reg-staged (float4 x4) -> f2bf -> ds_write into the same
// swizzled bf16 LDS layout; A stays global_load_lds. One barrier/K-step
// (attn-proven schedule). gu reads gate/up weights via row-split; down/patch
// use K guards. Saves ~150us of serial cvt + 6 launches each call.

typedef __bf16 bf16x8 __attribute__((ext_vector_type(8)));
typedef float  f32x4  __attribute__((ext_vector_type(4)));
typedef unsigned short u16;

#define DEV __device__ __forceinline__

DEV u16 f2bf(float f) {                       // RNE f32 -> bf16 bits
    union { float f; unsigned u; } v; v.f = f;
    unsigned r = v.u + 0x7FFFu + ((v.u >> 16) & 1u);
    return (u16)(r >> 16);
}
DEV float bf2f(u16 b) {
    union { float f; unsigned u; } v; v.u = ((unsigned)b) << 16; return v.f;
}

DEV void gload16(const u16* g, u16* l) {      // async global->LDS, 16B/lane
    __builtin_amdgcn_global_load_lds(
        (const __attribute__((address_space(1))) unsigned int*)g,
        (__attribute__((address_space(3))) unsigned int*)l, 16, 0, 0);
}

enum { EPI_NONE = 0, EPI_BIAS = 1, EPI_BIAS_RESID = 2, EPI_BIAS_GELU = 3, EPI_PART = 4 };

DEV unsigned xcd_map(unsigned lin, unsigned nwg) {
    unsigned q = nwg >> 3, r = nwg & 7, xc = lin & 7, off = lin >> 3;
    return (xc < r ? xc * (q + 1) : r * (q + 1) + (xc - r) * q) + off;
}

// f32 -> bf16 convert with zero-padding (pixels only now).
__global__ void cvt_kernel(const float* __restrict__ src, u16* __restrict__ dst,
                           int Rs, int Cs, int Rp, int Cp)
{
    int idx = blockIdx.x * 256 + threadIdx.x;
    int cpc = Cp >> 3;
    if (idx >= Rp * cpc) return;
    int row = idx / cpc;
    int c0  = (idx - row * cpc) * 8;
    u16 v[8];
    if (row < Rs && c0 + 8 <= Cs) {
        float4 a = *reinterpret_cast<const float4*>(&src[(size_t)row * Cs + c0]);
        float4 b = *reinterpret_cast<const float4*>(&src[(size_t)row * Cs + c0 + 4]);
        v[0] = f2bf(a.x); v[1] = f2bf(a.y); v[2] = f2bf(a.z); v[3] = f2bf(a.w);
        v[4] = f2bf(b.x); v[5] = f2bf(b.y); v[6] = f2bf(b.z); v[7] = f2bf(b.w);
    } else {
#pragma unroll
        for (int j = 0; j < 8; ++j) {
            int c = c0 + j;
            v[j] = (row < Rs && c < Cs) ? f2bf(src[(size_t)row * Cs + c]) : (u16)0;
        }
    }
    *reinterpret_cast<uint4*>(&dst[(size_t)row * Cp + c0]) =
        *reinterpret_cast<const uint4*>(v);
}

// Combined gate|up padded bias: [4][6912] f32.
__global__ void gub_kernel(const float* __restrict__ gb, const float* __restrict__ ub,
                           float* __restrict__ dst)
{
    int i = blockIdx.x * 256 + threadIdx.x;
    if (i >= 4 * 6912) return;
    int l = i / 6912, c = i - l * 6912;
    float v = 0.f;
    if (c < 3456) { if (c < 3420) v = gb[l * 3420 + c]; }
    else { int c2 = c - 3456; if (c2 < 3420) v = ub[l * 3420 + c2]; }
    dst[i] = v;
}

// out(RxC) = A(RxKpA bf16) @ B(f32, rows via B0/B1 split)^T. 128x128 tile,
// BK=32. A: global_load_lds double-buffer; B: reg-staged f32->bf16 into
// swizzled LDS. One barrier per K-step. Split-K via blockIdx.z (EPI_PART).
template <int EPI, bool OF32>
__global__ __launch_bounds__(256, 3)
void gemm16f_kernel(const u16* __restrict__ A, const float* __restrict__ B0,
                    const float* __restrict__ B1, int Bsplit, int BvalidRows,
                    int KpA, int Klog,
                    const float* __restrict__ bias, const float* __restrict__ resid,
                    void* __restrict__ outp, int ldc, int Rlim,
                    int ktn, size_t zstride)
{
    __shared__ u16 sA[2][4096];
    __shared__ u16 sB[2][4096];
    const int tid  = threadIdx.x;
    const int lane = tid & 63;
    const int w    = tid >> 6;

    const unsigned gy  = gridDim.y;
    const unsigned nwg = gridDim.x * gy;
    const unsigned lin = blockIdx.x + blockIdx.y * gridDim.x;
    const unsigned id2 = xcd_map(lin, nwg);
    const int c0 = (int)(id2 / gy) * 128;
    const int r0 = (int)(id2 - (id2 / gy) * gy) * 128;

    const int wr  = (w >> 1) * 64;
    const int wc  = (w & 1) * 64;
    const int l15 = lane & 15;
    const int kk  = (lane >> 4) * 8;
    const int pco = (((lane >> 4) ^ ((l15 >> 1) & 3)) * 8) - kk;

    // A staging: chunks tid, tid+256 (16B each), swizzled global source
    const int ca0 = tid, ca1 = tid + 256;
    const int ar0 = ca0 >> 2, ar1 = ca1 >> 2;
    const int alq0 = ((ca0 & 3) ^ ((ar0 >> 1) & 3)) * 8;
    const int alq1 = ((ca1 & 3) ^ ((ar1 >> 1) & 3)) * 8;
    const size_t asrc0 = (size_t)(r0 + ar0) * KpA + alq0;
    const size_t asrc1 = (size_t)(r0 + ar1) * KpA + alq1;

    // B staging: bf16-chunks tid, tid+256; f32 row pointers with split map
    const int cb0 = tid, cb1 = tid + 256;
    const int br0 = cb0 >> 2, br1 = cb1 >> 2;
    const int blq0 = ((cb0 & 3) ^ ((br0 >> 1) & 3)) * 8;
    const int blq1 = ((cb1 & 3) ^ ((br1 >> 1) & 3)) * 8;
    bool bv0, bv1;
    const float *bp0, *bp1;
    {
        int gr = c0 + br0; int hs = gr >= Bsplit; int lr = gr - (hs ? Bsplit : 0);
        bv0 = lr < BvalidRows; bp0 = (hs ? B1 : B0) + (size_t)lr * Klog + blq0;
        gr = c0 + br1; hs = gr >= Bsplit; lr = gr - (hs ? Bsplit : 0);
        bv1 = lr < BvalidRows; bp1 = (hs ? B1 : B0) + (size_t)lr * Klog + blq1;
    }

    f32x4 acc[4][4];
#pragma unroll
    for (int i = 0; i < 4; ++i)
#pragma unroll
        for (int j = 0; j < 4; ++j) acc[i][j] = (f32x4){0.f, 0.f, 0.f, 0.f};

    const int kt0 = blockIdx.z * ktn;
    float4 f00, f01, f10, f11;
    auto LOADB = [&](int kt) {
        int k0 = kt * 32;
        if (bv0) { f00 = *reinterpret_cast<const float4*>(bp0 + k0);
                   f01 = *reinterpret_cast<const float4*>(bp0 + k0 + 4); }
        else     { f00 = make_float4(0.f,0.f,0.f,0.f); f01 = f00; }
        if (bv1) { f10 = *reinterpret_cast<const float4*>(bp1 + k0);
                   f11 = *reinterpret_cast<const float4*>(bp1 + k0 + 4); }
        else     { f10 = make_float4(0.f,0.f,0.f,0.f); f11 = f10; }
    };
    auto WRITEB = [&](int s) {
        u16 h8[8];
        h8[0]=f2bf(f00.x); h8[1]=f2bf(f00.y); h8[2]=f2bf(f00.z); h8[3]=f2bf(f00.w);
        h8[4]=f2bf(f01.x); h8[5]=f2bf(f01.y); h8[6]=f2bf(f01.z); h8[7]=f2bf(f01.w);
        *reinterpret_cast<uint4*>(&sB[s][cb0 * 8]) = *reinterpret_cast<const uint4*>(h8);
        h8[0]=f2bf(f10.x); h8[1]=f2bf(f10.y); h8[2]=f2bf(f10.z); h8[3]=f2bf(f10.w);
        h8[4]=f2bf(f11.x); h8[5]=f2bf(f11.y); h8[6]=f2bf(f11.z); h8[7]=f2bf(f11.w);
        *reinterpret_cast<uint4*>(&sB[s][cb1 * 8]) = *reinterpret_cast<const uint4*>(h8);
    };
    auto stageA = [&](int kt, int s) {
        int k0 = kt * 32;
        gload16(A + asrc0 + k0, &sA[s][ca0 * 8]);
        gload16(A + asrc1 + k0, &sA[s][ca1 * 8]);
    };
    auto compute = [&](int s) {
        bf16x8 af[4], bfr[4];
#pragma unroll
        for (int f = 0; f < 4; ++f) {
            af[f]  = *reinterpret_cast<const bf16x8*>(&sA[s][(wr + f * 16 + l15) * 32 + kk + pco]);
            bfr[f] = *reinterpret_cast<const bf16x8*>(&sB[s][(wc + f * 16 + l15) * 32 + kk + pco]);
        }
#pragma unroll
        for (int fr = 0; fr < 4; ++fr)
#pragma unroll
            for (int fc = 0; fc < 4; ++fc)
                acc[fr][fc] = __builtin_amdgcn_mfma_f32_16x16x32_bf16(af[fr], bfr[fc], acc[fr][fc], 0, 0, 0);
    };

    const int NT = ktn;
    LOADB(kt0);
    stageA(kt0, 0);
    WRITEB(0);
    stageA(kt0 + 1, 1);
    LOADB(kt0 + 1);
    __syncthreads();
    int s = 0;
    for (int t = 0; t < NT; ++t) {
        compute(s);
        if (t + 1 < NT) WRITEB(s ^ 1);
        __syncthreads();
        if (t + 2 < NT) { stageA(kt0 + t + 2, s); LOADB(kt0 + t + 2); }
        s ^= 1;
    }

    const int rowb = r0 + wr + (lane >> 4) * 4;
    const int colb = c0 + wc + l15;
    if (EPI == EPI_PART) {
        float* pp = (float*)outp + (size_t)blockIdx.z * zstride;
#pragma unroll
        for (int fc = 0; fc < 4; ++fc) {
            int col = colb + fc * 16;
#pragma unroll
            for (int fr = 0; fr < 4; ++fr)
#pragma unroll
                for (int r2 = 0; r2 < 4; ++r2)
                    pp[(size_t)(rowb + fr * 16 + r2) * ldc + col] = acc[fr][fc][r2];
        }
        return;
    }
#pragma unroll
    for (int fc = 0; fc < 4; ++fc) {
        int col = colb + fc * 16;
        float bv = (EPI != EPI_NONE) ? bias[col] : 0.f;
#pragma unroll
        for (int fr = 0; fr < 4; ++fr) {
#pragma unroll
            for (int r2 = 0; r2 < 4; ++r2) {
                int row = rowb + fr * 16 + r2;
                if (row >= Rlim) continue;
                float v = acc[fr][fc][r2] + bv;
                if (EPI == EPI_BIAS_RESID) v += resid[(size_t)row * ldc + col];
                if (EPI == EPI_BIAS_GELU)  v = 0.5f * v * (1.f + erff(v * 0.70710678118f));
                if (OF32) ((float*)outp)[(size_t)row * ldc + col] = v;
                else      ((u16*)outp)[(size_t)row * ldc + col] = f2bf(v);
            }
        }
    }
}

// 32x128 tile, f32 B with K guard (Klog may be < KpA and non-mult-of-32).
template <int EPI, bool OF32>
__global__ __launch_bounds__(256, 4)
void gemm32f_kernel(const u16* __restrict__ A, const float* __restrict__ B,
                    int KpA, int Klog,
                    const float* __restrict__ bias, const float* __restrict__ resid,
                    void* __restrict__ outp, int ldc, int Rlim)
{
    __shared__ u16 sA[2][1024];
    __shared__ u16 sB[2][4096];
    const int tid  = threadIdx.x;
    const int lane = tid & 63;
    const int w    = tid >> 6;

    const unsigned gy  = gridDim.y;
    const unsigned nwg = gridDim.x * gy;
    const unsigned lin = blockIdx.x + blockIdx.y * gridDim.x;
    const unsigned id2 = xcd_map(lin, nwg);
    const int c0 = (int)(id2 / gy) * 128;
    const int r0 = (int)(id2 - (id2 / gy) * gy) * 32;

    const int wc  = w * 32;
    const int l15 = lane & 15;
    const int kk  = (lane >> 4) * 8;
    const int pco = (((lane >> 4) ^ ((l15 >> 1) & 3)) * 8) - kk;

    // A staging (bf16, gload_lds): 128 chunks, tid<128
    const int ca = tid & 127;
    const int aro = ca >> 2;
    const int alq = ((ca & 3) ^ ((aro >> 1) & 3)) * 8;
    const size_t asrc = (size_t)(r0 + aro) * KpA + alq;

    // B staging: bf16-chunks tid, tid+256 -> f32 source with k guard
    const int cb0 = tid, cb1 = tid + 256;
    const int br0 = cb0 >> 2, br1 = cb1 >> 2;
    const int blq0 = ((cb0 & 3) ^ ((br0 >> 1) & 3)) * 8;
    const int blq1 = ((cb1 & 3) ^ ((br1 >> 1) & 3)) * 8;
    const float* bp0 = B + (size_t)(c0 + br0) * Klog;
    const float* bp1 = B + (size_t)(c0 + br1) * Klog;

    f32x4 acc[2][2];
#pragma unroll
    for (int i = 0; i < 2; ++i)
#pragma unroll
        for (int j = 0; j < 2; ++j) acc[i][j] = (f32x4){0.f, 0.f, 0.f, 0.f};

    float4 f00, f01, f10, f11;
    auto ldchunk = [&](const float* bp, int ks, float4& a, float4& b) {
        if (ks + 8 <= Klog) {
            a = *reinterpret_cast<const float4*>(bp + ks);
            b = *reinterpret_cast<const float4*>(bp + ks + 4);
        } else {
            float t[8];
#pragma unroll
            for (int e = 0; e < 8; ++e) t[e] = (ks + e < Klog) ? bp[ks + e] : 0.f;
            a = make_float4(t[0], t[1], t[2], t[3]);
            b = make_float4(t[4], t[5], t[6], t[7]);
        }
    };
    auto LOADB = [&](int kt) {
        int k0 = kt * 32;
        ldchunk(bp0, k0 + blq0, f00, f01);
        ldchunk(bp1, k0 + blq1, f10, f11);
    };
    auto WRITEB = [&](int s) {
        u16 h8[8];
        h8[0]=f2bf(f00.x); h8[1]=f2bf(f00.y); h8[2]=f2bf(f00.z); h8[3]=f2bf(f00.w);
        h8[4]=f2bf(f01.x); h8[5]=f2bf(f01.y); h8[6]=f2bf(f01.z); h8[7]=f2bf(f01.w);
        *reinterpret_cast<uint4*>(&sB[s][cb0 * 8]) = *reinterpret_cast<const uint4*>(h8);
        h8[0]=f2bf(f10.x); h8[1]=f2bf(f10.y); h8[2]=f2bf(f10.z); h8[3]=f2bf(f10.w);
        h8[4]=f2bf(f11.x); h8[5]=f2bf(f11.y); h8[6]=f2bf(f11.z); h8[7]=f2bf(f11.w);
        *reinterpret_cast<uint4*>(&sB[s][cb1 * 8]) = *reinterpret_cast<const uint4*>(h8);
    };
    auto stageA = [&](int kt, int s) {
        if (tid < 128) gload16(A + asrc + kt * 32, &sA[s][ca * 8]);
    };
    auto compute = [&](int s) {
        bf16x8 af[2], bfr[2];
#pragma unroll
        for (int f = 0; f < 2; ++f) {
            af[f]  = *reinterpret_cast<const bf16x8*>(&sA[s][(f * 16 + l15) * 32 + kk + pco]);
            bfr[f] = *reinterpret_cast<const bf16x8*>(&sB[s][(wc + f * 16 + l15) * 32 + kk + pco]);
        }
#pragma unroll
        for (int fr = 0; fr < 2; ++fr)
#pragma unroll
            for (int fc = 0; fc < 2; ++fc)
                acc[fr][fc] = __builtin_amdgcn_mfma_f32_16x16x32_bf16(af[fr], bfr[fc], acc[fr][fc], 0, 0, 0);
    };

    const int NT = KpA >> 5;
    LOADB(0);
    stageA(0, 0);
    WRITEB(0);
    stageA(1, 1);
    LOADB(1);
    __syncthreads();
    int s = 0;
    for (int t = 0; t < NT; ++t) {
        compute(s);
        if (t + 1 < NT) WRITEB(s ^ 1);
        __syncthreads();
        if (t + 2 < NT) { stageA(t + 2, s); LOADB(t + 2); }
        s ^= 1;
    }

    const int rowb = r0 + (lane >> 4) * 4;
    const int colb = c0 + wc + l15;
#pragma unroll
    for (int fc = 0; fc < 2; ++fc) {
        int col = colb + fc * 16;
        float bv = (EPI != EPI_NONE) ? bias[col] : 0.f;
#pragma unroll
        for (int fr = 0; fr < 2; ++fr) {
#pragma unroll
            for (int r2 = 0; r2 < 4; ++r2) {
                int row = rowb + fr * 16 + r2;
                if (row >= Rlim) continue;
                float v = acc[fr][fc][r2] + bv;
                if (EPI == EPI_BIAS_RESID) v += resid[(size_t)row * ldc + col];
                if (EPI == EPI_BIAS_GELU)  v = 0.5f * v * (1.f + erff(v * 0.70710678118f));
                if (OF32) ((float*)outp)[(size_t)row * ldc + col] = v;
                else      ((u16*)outp)[(size_t)row * ldc + col] = f2bf(v);
            }
        }
    }
}

// Split-K reduce: out = [gelu](sum_s part[s] + bias). total4 = R*C/4.
template <int GELU, bool OF32>
__global__ void reduce_kernel(const float* __restrict__ part, const float* __restrict__ bias,
                              void* __restrict__ outp, int C, int S, size_t zstride, int total4)
{
    int i = blockIdx.x * 256 + threadIdx.x;
    if (i >= total4) return;
    int cq = C >> 2;
    int rr = i / cq;
    int cc = (i - rr * cq) * 4;
    size_t bidx = (size_t)rr * C + cc;
    float4 s = *reinterpret_cast<const float4*>(&part[bidx]);
    for (int z = 1; z < S; ++z) {
        float4 p = *reinterpret_cast<const float4*>(&part[z * zstride + bidx]);
        s.x += p.x; s.y += p.y; s.z += p.z; s.w += p.w;
    }
    float4 b = *reinterpret_cast<const float4*>(&bias[cc]);
    s.x += b.x; s.y += b.y; s.z += b.z; s.w += b.w;
    if (GELU) {
        s.x = 0.5f * s.x * (1.f + erff(s.x * 0.70710678118f));
        s.y = 0.5f * s.y * (1.f + erff(s.y * 0.70710678118f));
        s.z = 0.5f * s.z * (1.f + erff(s.z * 0.70710678118f));
        s.w = 0.5f * s.w * (1.f + erff(s.w * 0.70710678118f));
    }
    if (OF32) {
        *reinterpret_cast<float4*>(&((float*)outp)[bidx]) = s;
    } else {
        u16 v[4] = { f2bf(s.x), f2bf(s.y), f2bf(s.z), f2bf(s.w) };
        *reinterpret_cast<uint2*>(&((u16*)outp)[bidx]) = *reinterpret_cast<const uint2*>(v);
    }
}

__global__ void rms_kernel(const float* __restrict__ x, const float* __restrict__ w,
                           u16* __restrict__ out, int cols)
{
    const int row = blockIdx.x;
    const int tid = threadIdx.x;
    const float* xr = x + (size_t)row * cols;
    float ss = 0.f;
    for (int c = tid; c < cols; c += 256) { float v = xr[c]; ss += v * v; }
#pragma unroll
    for (int m = 1; m < 64; m <<= 1) ss += __shfl_xor(ss, m);
    __shared__ float wsum[4];
    if ((tid & 63) == 0) wsum[tid >> 6] = ss;
    __syncthreads();
    float tot = wsum[0] + wsum[1] + wsum[2] + wsum[3];
    float rs = rsqrtf(tot / (float)cols + 1e-6f);
    u16* orow = out + (size_t)row * cols;
    for (int c = tid; c < cols; c += 256) orow[c] = f2bf(xr[c] * rs * w[c]);
}

// In-place RoPE on bf16 q,k halves of qkv.
__global__ void rope_kernel(u16* __restrict__ qkv, const float* __restrict__ cosb,
                            const float* __restrict__ sinb)
{
    int idx = blockIdx.x * 256 + threadIdx.x;   // < 1,024,000
    int n   = idx / 640;
    int rem = idx - n * 640;
    int hh  = rem / 40;
    int d   = rem - hh * 40;
    float c0 = cosb[n * 80 + d];
    float s0 = sinb[n * 80 + d];
    float c1 = cosb[n * 80 + d + 40];
    float s1 = sinb[n * 80 + d + 40];
    size_t base = (size_t)n * 3840 + hh * 80;
    float a = bf2f(qkv[base + d]), b = bf2f(qkv[base + d + 40]);
    qkv[base + d]      = f2bf(a * c0 - b * s0);
    qkv[base + d + 40] = f2bf(b * c1 + a * s1);
    base += 1280;
    a = bf2f(qkv[base + d]); b = bf2f(qkv[base + d + 40]);
    qkv[base + d]      = f2bf(a * c0 - b * s0);
    qkv[base + d + 40] = f2bf(b * c1 + a * s1);
}

// silu(gate)*up from fused [1664][6912] buffer -> packed [1664][3456].
__global__ void silu_mul_kernel(const u16* __restrict__ gu, u16* __restrict__ outb)
{
    int idx = blockIdx.x * 256 + threadIdx.x;
    if (idx >= 1664 * 432) return;
    int row = idx / 432, c8 = (idx - row * 432) * 8;
    u16 gv[8], uv[8];
    *reinterpret_cast<uint4*>(gv) = *reinterpret_cast<const uint4*>(&gu[(size_t)row * 6912 + c8]);
    *reinterpret_cast<uint4*>(uv) = *reinterpret_cast<const uint4*>(&gu[(size_t)row * 6912 + 3456 + c8]);
#pragma unroll
    for (int j = 0; j < 8; ++j) {
        float x = bf2f(gv[j]);
        gv[j] = f2bf(x / (1.f + __expf(-x)) * bf2f(uv[j]));
    }
    *reinterpret_cast<uint4*>(&outb[(size_t)row * 3456 + c8]) = *reinterpret_cast<const uint4*>(gv);
}

// Flash attention v2 (unchanged from r7).
__global__ __launch_bounds__(256, 2)
void attn_kernel(const u16* __restrict__ qkv, u16* __restrict__ o)
{
    __shared__ __align__(16) u16      Klds[2][64][104];
    __shared__ __align__(16) unsigned Vt32[2][80][36];
    __shared__ __align__(16) u16      Plds[4][16][72];
    const int tid  = threadIdx.x;
    const int lane = tid & 63;
    const int w    = tid >> 6;
    const int l15  = lane & 15;
    const int kk   = (lane >> 4) * 8;
    unsigned lin = blockIdx.y * 25 + blockIdx.x;
    unsigned id2 = (lin & 7) * 50 + (lin >> 3);
    const int hh = (int)(id2 / 25);
    const int qt = (int)(id2 - hh * 25);
    const float scale = 0.11180339887498949f;

    const int koff = 1280 + hh * 80;
    const int voff = 2560 + hh * 80;

    {
        int r  = tid >> 2;
        int cq = 80 + (tid & 3) * 4;
        *reinterpret_cast<uint2*>(&Klds[0][r][cq]) = make_uint2(0u, 0u);
        *reinterpret_cast<uint2*>(&Klds[1][r][cq]) = make_uint2(0u, 0u);
    }

    const int qrow = qt * 64 + w * 16 + l15;
    bf16x8 aq[3];
#pragma unroll
    for (int s = 0; s < 3; ++s) {
        int d = 32 * s + kk;
        union { bf16x8 v; uint4 q; } uu;
        if (d < 80) uu.q = *reinterpret_cast<const uint4*>(&qkv[(size_t)qrow * 3840 + hh * 80 + d]);
        else        uu.q = make_uint4(0u, 0u, 0u, 0u);
        aq[s] = uu.v;
    }

    const int kc0 = tid, kc1 = tid + 256, kc2 = tid + 512;
    const int kr0 = kc0 / 10, k80 = (kc0 - kr0 * 10) * 8;
    const int kr1 = kc1 / 10, k81 = (kc1 - kr1 * 10) * 8;
    const int kr2 = kc2 / 10, k82 = (kc2 - kr2 * 10) * 8;
    const size_t ksrc0 = (size_t)kr0 * 3840 + koff + k80;
    const size_t ksrc1 = (size_t)kr1 * 3840 + koff + k81;
    const size_t ksrc2 = (size_t)kr2 * 3840 + koff + k82;
    const int rpA = tid & 31, gA = tid >> 5;
    const int gB = 8 + (tid >> 5);
    const size_t vsrcA = (size_t)(2 * rpA) * 3840 + voff + gA * 8;
    const size_t vsrcB = (size_t)(2 * rpA) * 3840 + voff + gB * 8;

    uint4 kg0, kg1, kg2, va0, va1, vb0, vb1;
    auto LOADR = [&](int kb) {
        size_t tb = (size_t)kb * 245760;
        kg0 = *reinterpret_cast<const uint4*>(&qkv[tb + ksrc0]);
        kg1 = *reinterpret_cast<const uint4*>(&qkv[tb + ksrc1]);
        if (tid < 128) kg2 = *reinterpret_cast<const uint4*>(&qkv[tb + ksrc2]);
        va0 = *reinterpret_cast<const uint4*>(&qkv[tb + vsrcA]);
        va1 = *reinterpret_cast<const uint4*>(&qkv[tb + vsrcA + 3840]);
        if (tid < 64) {
            vb0 = *reinterpret_cast<const uint4*>(&qkv[tb + vsrcB]);
            vb1 = *reinterpret_cast<const uint4*>(&qkv[tb + vsrcB + 3840]);
        }
    };
    auto STORE = [&](int b) {
        *reinterpret_cast<uint4*>(&Klds[b][kr0][k80]) = kg0;
        *reinterpret_cast<uint4*>(&Klds[b][kr1][k81]) = kg1;
        if (tid < 128) *reinterpret_cast<uint4*>(&Klds[b][kr2][k82]) = kg2;
        union { uint4 q; u16 h[8]; } xa0, xa1;
        xa0.q = va0; xa1.q = va1;
#pragma unroll
        for (int j = 0; j < 8; ++j)
            Vt32[b][gA * 8 + j][rpA] = (unsigned)xa0.h[j] | ((unsigned)xa1.h[j] << 16);
        if (tid < 64) {
            union { uint4 q; u16 h[8]; } xb0, xb1;
            xb0.q = vb0; xb1.q = vb1;
#pragma unroll
            for (int j = 0; j < 8; ++j)
                Vt32[b][gB * 8 + j][rpA] = (unsigned)xb0.h[j] | ((unsigned)xb1.h[j] << 16);
        }
    };

    f32x4 acc_o[5];
#pragma unroll
    for (int fd = 0; fd < 5; ++fd) acc_o[fd] = (f32x4){0.f, 0.f, 0.f, 0.f};
    float m[4], lsum[4];
#pragma unroll
    for (int r2 = 0; r2 < 4; ++r2) { m[r2] = -__builtin_inff(); lsum[r2] = 0.f; }

    LOADR(0);
    STORE(0);
    __syncthreads();
    int cur = 0;

    for (int kb = 0; kb < 25; ++kb) {
        if (kb < 24) LOADR(kb + 1);

        f32x4 sf[4];
#pragma unroll
        for (int fc = 0; fc < 4; ++fc) {
            f32x4 c = (f32x4){0.f, 0.f, 0.f, 0.f};
#pragma unroll
            for (int s = 0; s < 3; ++s)
                c = __builtin_amdgcn_mfma_f32_16x16x32_bf16(
                        aq[s],
                        *reinterpret_cast<const bf16x8*>(&Klds[cur][fc * 16 + l15][32 * s + kk]),
                        c, 0, 0, 0);
            sf[fc] = c * scale;
        }

        float mx[4];
#pragma unroll
        for (int r2 = 0; r2 < 4; ++r2)
            mx[r2] = fmaxf(fmaxf(sf[0][r2], sf[1][r2]), fmaxf(sf[2][r2], sf[3][r2]));
#pragma unroll
        for (int msk = 1; msk <= 8; msk <<= 1)
#pragma unroll
            for (int r2 = 0; r2 < 4; ++r2)
                mx[r2] = fmaxf(mx[r2], __shfl_xor(mx[r2], msk));
        float alpha[4];
#pragma unroll
        for (int r2 = 0; r2 < 4; ++r2) {
            float mn = fmaxf(m[r2], mx[r2]);
            alpha[r2] = __expf(m[r2] - mn);
            m[r2] = mn;
        }
        float psum[4] = {0.f, 0.f, 0.f, 0.f};
#pragma unroll
        for (int fc = 0; fc < 4; ++fc)
#pragma unroll
            for (int r2 = 0; r2 < 4; ++r2) {
                float p = __expf(sf[fc][r2] - m[r2]);
                sf[fc][r2] = p;
                psum[r2] += p;
            }
#pragma unroll
        for (int msk = 1; msk <= 8; msk <<= 1)
#pragma unroll
            for (int r2 = 0; r2 < 4; ++r2) psum[r2] += __shfl_xor(psum[r2], msk);
#pragma unroll
        for (int r2 = 0; r2 < 4; ++r2) lsum[r2] = lsum[r2] * alpha[r2] + psum[r2];
#pragma unroll
        for (int fd = 0; fd < 5; ++fd)
#pragma unroll
            for (int r2 = 0; r2 < 4; ++r2) acc_o[fd][r2] *= alpha[r2];

        const int prow = (lane >> 4) * 4;
#pragma unroll
        for (int fc = 0; fc < 4; ++fc)
#pragma unroll
            for (int r2 = 0; r2 < 4; ++r2)
                Plds[w][prow + r2][fc * 16 + l15] = f2bf(sf[fc][r2]);

        bf16x8 ap[2];
#pragma unroll
        for (int ks = 0; ks < 2; ++ks)
            ap[ks] = *reinterpret_cast<const bf16x8*>(&Plds[w][l15][32 * ks + kk]);
#pragma unroll
        for (int fd = 0; fd < 5; ++fd) {
            const u16* vrow = reinterpret_cast<const u16*>(&Vt32[cur][fd * 16 + l15][0]);
#pragma unroll
            for (int ks = 0; ks < 2; ++ks)
                acc_o[fd] = __builtin_amdgcn_mfma_f32_16x16x32_bf16(
                        ap[ks],
                        *reinterpret_cast<const bf16x8*>(&vrow[32 * ks + kk]),
                        acc_o[fd], 0, 0, 0);
        }

        if (kb < 24) STORE(cur ^ 1);
        __syncthreads();
        cur ^= 1;
    }

    float inv[4];
#pragma unroll
    for (int r2 = 0; r2 < 4; ++r2) inv[r2] = 1.f / lsum[r2];
    const int orow = qt * 64 + w * 16 + (lane >> 4) * 4;
    const int ocol = hh * 80 + l15;
#pragma unroll
    for (int fd = 0; fd < 5; ++fd)
#pragma unroll
        for (int r2 = 0; r2 < 4; ++r2)
            o[(size_t)(orow + r2) * 1280 + ocol + fd * 16] = f2bf(acc_o[fd][r2] * inv[r2]);
}

extern "C" void kernel_launch(void* const* d_in, const int* in_sizes, int n_in,
                              void* d_out, int out_size, void* d_ws, size_t ws_size,
                              hipStream_t stream)
{
    const float* pixel  = (const float*)d_in[0];
    const float* cosb   = (const float*)d_in[1];
    const float* sinb   = (const float*)d_in[2];
    const float* patchw = (const float*)d_in[3];
    const float* n1w    = (const float*)d_in[4];
    const float* qkvw   = (const float*)d_in[5];
    const float* qkvb   = (const float*)d_in[6];
    const float* projw  = (const float*)d_in[7];
    const float* projb  = (const float*)d_in[8];
    const float* n2w    = (const float*)d_in[9];
    const float* gatew  = (const float*)d_in[10];
    const float* gateb  = (const float*)d_in[11];
    const float* upw    = (const float*)d_in[12];
    const float* upb    = (const float*)d_in[13];
    const float* downw  = (const float*)d_in[14];
    const float* downb  = (const float*)d_in[15];
    const float* lnqw   = (const float*)d_in[16];
    const float* m1w    = (const float*)d_in[17];
    const float* m1b    = (const float*)d_in[18];
    const float* m2w    = (const float*)d_in[19];
    const float* m2b    = (const float*)d_in[20];
    float* out = (float*)d_out;

    char* base = (char*)d_ws;
    float* x    = (float*)(base);                 // 1664x1280 f32
    u16*   h    = (u16*)(base + 8519680);         // 1664x1280
    u16*   qbuf = (u16*)(base + 12779520);        // 1664x3840
    u16*   pix16= (u16*)(base + 25559040);        // 1664x1184
    u16*   gsep = (u16*)(base + 29499392);        // 1664x3456
    u16*   o    = gsep;                           // alias (attn->proj)
    u16*   gu   = (u16*)(base + 41000960);        // 1664x6912
    u16*   t1   = gu;                             // alias (post-loop, 512x5120)
    float* guB  = (float*)(base + 64004096);      // 4x6912 f32
    float* part = (float*)(base + 64114688);      // 52.4MB split-K partials

    dim3 blk(256);
    const int BIG = 1 << 28;

    cvt_kernel<<<963, blk, 0, stream>>>(pixel, pix16, 1600, 1176, 1664, 1184);
    gub_kernel<<<108, blk, 0, stream>>>(gateb, upb, guB);

    gemm32f_kernel<EPI_NONE, true><<<dim3(10,52), blk, 0, stream>>>(
        pix16, patchw, 1184, 1176, nullptr, nullptr, x, 1280, 1664);
    for (int i = 0; i < 4; ++i) {
        rms_kernel<<<1600, blk, 0, stream>>>(x, n1w + i*1280, h, 1280);
        gemm16f_kernel<EPI_BIAS, false><<<dim3(30,13), blk, 0, stream>>>(
            h, qkvw + (size_t)i*4915200, nullptr, BIG, BIG, 1280, 1280,
            qkvb + i*3840, nullptr, qbuf, 3840, 1664, 40, 0);
        rope_kernel<<<4000, blk, 0, stream>>>(qbuf, cosb, sinb);
        attn_kernel<<<dim3(25,16), blk, 0, stream>>>(qbuf, o);
        gemm32f_kernel<EPI_BIAS_RESID, true><<<dim3(10,52), blk, 0, stream>>>(
            o, projw + (size_t)i*1638400, 1280, 1280,
            projb + i*1280, x, x, 1280, 1664);
        rms_kernel<<<1600, blk, 0, stream>>>(x, n2w + i*1280, h, 1280);
        gemm16f_kernel<EPI_BIAS, false><<<dim3(54,13), blk, 0, stream>>>(
            h, gatew + (size_t)i*4377600, upw + (size_t)i*4377600, 3456, 3420, 1280, 1280,
            guB + i*6912, nullptr, gu, 6912, 1664, 40, 0);
        silu_mul_kernel<<<2808, blk, 0, stream>>>(gu, gsep);
        gemm32f_kernel<EPI_BIAS_RESID, true><<<dim3(10,52), blk, 0, stream>>>(
            gsep, downw + (size_t)i*4377600, 3456, 3420,
            downb + i*1280, x, x, 1280, 1664);
    }
    rms_kernel<<<1600, blk, 0, stream>>>(x, lnqw, h, 1280);
    gemm16f_kernel<EPI_PART, false><<<dim3(40,4,5), blk, 0, stream>>>(
        h, m1w, nullptr, BIG, BIG, 5120, 5120,
        nullptr, nullptr, part, 5120, 512, 32, 2621440);
    reduce_kernel<1, false><<<2560, blk, 0, stream>>>(part, m1b, t1, 5120, 5, 2621440, 655360);
    gemm16f_kernel<EPI_PART, false><<<dim3(28,4,5), blk, 0, stream>>>(
        t1, m2w, nullptr, BIG, BIG, 5120, 5120,
        nullptr, nullptr, part, 3584, 512, 32, 1835008);
    reduce_kernel<0, true><<<1400, blk, 0, stream>>>(part, m2b, out, 3584, 5, 1835008, 358400);
}

// Round 10
// 1562.341 us; speedup vs baseline: 1.4479x; 1.4479x over previous
//
#include <hip/hip_runtime.h>

// Qwen2.5-VL vision tower forward, MI355X gfx950 — round 9.
// r8's f32-direct GEMM regressed (exposed B-load latency) -> full revert to
// r7 structure (bf16 weight cvt + gload_lds ring-3), plus residency fix for
// the last two low-block-count GEMMs: qkv (30,13)->(30,52) and gate|up
// (54,13)->(54,52) via the 32x128-tile kernel (4 blocks/CU).

typedef __bf16 bf16x8 __attribute__((ext_vector_type(8)));
typedef float  f32x4  __attribute__((ext_vector_type(4)));
typedef unsigned short u16;

#define DEV __device__ __forceinline__

DEV u16 f2bf(float f) {                       // RNE f32 -> bf16 bits
    union { float f; unsigned u; } v; v.f = f;
    unsigned r = v.u + 0x7FFFu + ((v.u >> 16) & 1u);
    return (u16)(r >> 16);
}
DEV float bf2f(u16 b) {
    union { float f; unsigned u; } v; v.u = ((unsigned)b) << 16; return v.f;
}

DEV void gload16(const u16* g, u16* l) {      // async global->LDS, 16B/lane
    __builtin_amdgcn_global_load_lds(
        (const __attribute__((address_space(1))) unsigned int*)g,
        (__attribute__((address_space(3))) unsigned int*)l, 16, 0, 0);
}

enum { EPI_NONE = 0, EPI_BIAS = 1, EPI_BIAS_RESID = 2, EPI_BIAS_GELU = 3, EPI_PART = 4 };

DEV unsigned xcd_map(unsigned lin, unsigned nwg) {
    unsigned q = nwg >> 3, r = nwg & 7, xc = lin & 7, off = lin >> 3;
    return (xc < r ? xc * (q + 1) : r * (q + 1) + (xc - r) * q) + off;
}

// f32 -> bf16 convert with zero-padding; blockIdx.y = layer.
__global__ void cvt_kernel(const float* __restrict__ src, u16* __restrict__ dst,
                           int Rs, int Cs, int Rp, int Cp,
                           long long sls, long long dls)
{
    const float* s = src + (size_t)blockIdx.y * sls;
    u16* d = dst + (size_t)blockIdx.y * dls;
    int idx = blockIdx.x * 256 + threadIdx.x;
    int cpc = Cp >> 3;
    if (idx >= Rp * cpc) return;
    int row = idx / cpc;
    int c0  = (idx - row * cpc) * 8;
    u16 v[8];
    if (row < Rs && c0 + 8 <= Cs) {
        float4 a = *reinterpret_cast<const float4*>(&s[(size_t)row * Cs + c0]);
        float4 b = *reinterpret_cast<const float4*>(&s[(size_t)row * Cs + c0 + 4]);
        v[0] = f2bf(a.x); v[1] = f2bf(a.y); v[2] = f2bf(a.z); v[3] = f2bf(a.w);
        v[4] = f2bf(b.x); v[5] = f2bf(b.y); v[6] = f2bf(b.z); v[7] = f2bf(b.w);
    } else {
#pragma unroll
        for (int j = 0; j < 8; ++j) {
            int c = c0 + j;
            v[j] = (row < Rs && c < Cs) ? f2bf(s[(size_t)row * Cs + c]) : (u16)0;
        }
    }
    *reinterpret_cast<uint4*>(&d[(size_t)row * Cp + c0]) =
        *reinterpret_cast<const uint4*>(v);
}

// Combined gate|up padded bias: [4][6912] f32.
__global__ void gub_kernel(const float* __restrict__ gb, const float* __restrict__ ub,
                           float* __restrict__ dst)
{
    int i = blockIdx.x * 256 + threadIdx.x;
    if (i >= 4 * 6912) return;
    int l = i / 6912, c = i - l * 6912;
    float v = 0.f;
    if (c < 3456) { if (c < 3420) v = gb[l * 3420 + c]; }
    else { int c2 = c - 3456; if (c2 < 3420) v = ub[l * 3420 + c2]; }
    dst[i] = v;
}

// out(RxC) = A(RxKp) @ B(CxKp)^T, bf16 in. 128x128 tile, BK=32, ring-3 LDS,
// counted vmcnt, chunk-XOR swizzle. Split-K via blockIdx.z (EPI_PART).
template <int EPI, bool OF32>
__global__ __launch_bounds__(256, 3)
void gemm16_kernel(const u16* __restrict__ A, const u16* __restrict__ B,
                   const float* __restrict__ bias, const float* __restrict__ resid,
                   void* __restrict__ outp, int Kp, int ldc, int Rlim,
                   int ktn, size_t zstride)
{
    __shared__ u16 sA[3][4096];
    __shared__ u16 sB[3][4096];
    const int tid  = threadIdx.x;
    const int lane = tid & 63;
    const int w    = tid >> 6;

    const unsigned gy  = gridDim.y;
    const unsigned nwg = gridDim.x * gy;
    const unsigned lin = blockIdx.x + blockIdx.y * gridDim.x;  // HW dispatch order
    const unsigned id2 = xcd_map(lin, nwg);
    const int c0 = (int)(id2 / gy) * 128;
    const int r0 = (int)(id2 - (id2 / gy) * gy) * 128;

    const int wr  = (w >> 1) * 64;
    const int wc  = (w & 1) * 64;
    const int l15 = lane & 15;
    const int kk  = (lane >> 4) * 8;
    const int pco = (((lane >> 4) ^ ((l15 >> 1) & 3)) * 8) - kk;

    const int ca  = w * 128 + lane;
    const int cb  = ca + 64;
    const int sza = ((ca & 3) ^ ((ca >> 3) & 3)) * 8;
    const int szb = ((cb & 3) ^ ((cb >> 3) & 3)) * 8;
    const size_t arow0 = (size_t)(r0 + (ca >> 2)) * Kp + sza;
    const size_t brow0 = (size_t)(c0 + (ca >> 2)) * Kp + sza;
    const size_t arow1 = (size_t)(r0 + (cb >> 2)) * Kp + szb;
    const size_t brow1 = (size_t)(c0 + (cb >> 2)) * Kp + szb;

    f32x4 acc[4][4];
#pragma unroll
    for (int i = 0; i < 4; ++i)
#pragma unroll
        for (int j = 0; j < 4; ++j) acc[i][j] = (f32x4){0.f, 0.f, 0.f, 0.f};

    const int kt0 = blockIdx.z * ktn;
    auto stage = [&](int kt, int buf) {
        int k0 = kt * 32;
        gload16(A + arow0 + k0, &sA[buf][ca * 8]);
        gload16(B + brow0 + k0, &sB[buf][ca * 8]);
        gload16(A + arow1 + k0, &sA[buf][cb * 8]);
        gload16(B + brow1 + k0, &sB[buf][cb * 8]);
    };
    auto compute = [&](int buf) {
        bf16x8 af[4], bfr[4];
#pragma unroll
        for (int f = 0; f < 4; ++f) {
            af[f]  = *reinterpret_cast<const bf16x8*>(&sA[buf][(wr + f * 16 + l15) * 32 + kk + pco]);
            bfr[f] = *reinterpret_cast<const bf16x8*>(&sB[buf][(wc + f * 16 + l15) * 32 + kk + pco]);
        }
#pragma unroll
        for (int fr = 0; fr < 4; ++fr)
#pragma unroll
            for (int fc = 0; fc < 4; ++fc)
                acc[fr][fc] = __builtin_amdgcn_mfma_f32_16x16x32_bf16(af[fr], bfr[fc], acc[fr][fc], 0, 0, 0);
    };

    const int NT = ktn;
    stage(kt0, 0);
    if (NT > 1) stage(kt0 + 1, 1);
    int bcur = 0;
    for (int t = 0; t < NT - 1; ++t) {
        asm volatile("s_waitcnt vmcnt(4)" ::: "memory");
        __builtin_amdgcn_s_barrier();
        __builtin_amdgcn_sched_barrier(0);
        if (t + 2 < NT) {
            int bn = bcur + 2; if (bn >= 3) bn -= 3;
            stage(kt0 + t + 2, bn);
        }
        __builtin_amdgcn_sched_barrier(0);
        compute(bcur);
        bcur = (bcur == 2) ? 0 : bcur + 1;
    }
    asm volatile("s_waitcnt vmcnt(0)" ::: "memory");
    __builtin_amdgcn_s_barrier();
    __builtin_amdgcn_sched_barrier(0);
    compute(bcur);

    const int rowb = r0 + wr + (lane >> 4) * 4;
    const int colb = c0 + wc + l15;
    if (EPI == EPI_PART) {
        float* pp = (float*)outp + (size_t)blockIdx.z * zstride;
#pragma unroll
        for (int fc = 0; fc < 4; ++fc) {
            int col = colb + fc * 16;
#pragma unroll
            for (int fr = 0; fr < 4; ++fr)
#pragma unroll
                for (int r2 = 0; r2 < 4; ++r2)
                    pp[(size_t)(rowb + fr * 16 + r2) * ldc + col] = acc[fr][fc][r2];
        }
        return;
    }
#pragma unroll
    for (int fc = 0; fc < 4; ++fc) {
        int col = colb + fc * 16;
        float bv = (EPI != EPI_NONE) ? bias[col] : 0.f;
#pragma unroll
        for (int fr = 0; fr < 4; ++fr) {
#pragma unroll
            for (int r2 = 0; r2 < 4; ++r2) {
                int row = rowb + fr * 16 + r2;
                if (row >= Rlim) continue;
                float v = acc[fr][fc][r2] + bv;
                if (EPI == EPI_BIAS_RESID) v += resid[(size_t)row * ldc + col];
                if (EPI == EPI_BIAS_GELU)  v = 0.5f * v * (1.f + erff(v * 0.70710678118f));
                if (OF32) ((float*)outp)[(size_t)row * ldc + col] = v;
                else      ((u16*)outp)[(size_t)row * ldc + col] = f2bf(v);
            }
        }
    }
}

// 32x128-tile GEMM for residency-bound shapes. BK=32, ring-3, 3 gloads/thread.
template <int EPI, bool OF32>
__global__ __launch_bounds__(256, 4)
void gemm32_kernel(const u16* __restrict__ A, const u16* __restrict__ B,
                   const float* __restrict__ bias, const float* __restrict__ resid,
                   void* __restrict__ outp, int Kp, int ldc, int Rlim)
{
    __shared__ u16 sA[3][1024];
    __shared__ u16 sB[3][4096];
    const int tid  = threadIdx.x;
    const int lane = tid & 63;
    const int w    = tid >> 6;

    const unsigned gy  = gridDim.y;
    const unsigned nwg = gridDim.x * gy;
    const unsigned lin = blockIdx.x + blockIdx.y * gridDim.x;
    const unsigned id2 = xcd_map(lin, nwg);
    const int c0 = (int)(id2 / gy) * 128;
    const int r0 = (int)(id2 - (id2 / gy) * gy) * 32;

    const int wc  = w * 32;
    const int l15 = lane & 15;
    const int kk  = (lane >> 4) * 8;
    const int pco = (((lane >> 4) ^ ((l15 >> 1) & 3)) * 8) - kk;

    const int cB0 = tid, cB1 = tid + 256, cA = tid & 127;
    const size_t bsrc0 = (size_t)(c0 + (cB0 >> 2)) * Kp + ((cB0 & 3) ^ ((cB0 >> 3) & 3)) * 8;
    const size_t bsrc1 = (size_t)(c0 + (cB1 >> 2)) * Kp + ((cB1 & 3) ^ ((cB1 >> 3) & 3)) * 8;
    const size_t asrc  = (size_t)(r0 + (cA  >> 2)) * Kp + ((cA  & 3) ^ ((cA  >> 3) & 3)) * 8;

    f32x4 acc[2][2];
#pragma unroll
    for (int i = 0; i < 2; ++i)
#pragma unroll
        for (int j = 0; j < 2; ++j) acc[i][j] = (f32x4){0.f, 0.f, 0.f, 0.f};

    auto stage = [&](int kt, int buf) {
        int k0 = kt * 32;
        gload16(B + bsrc0 + k0, &sB[buf][cB0 * 8]);
        gload16(B + bsrc1 + k0, &sB[buf][cB1 * 8]);
        gload16(A + asrc  + k0, &sA[buf][cA * 8]);
    };
    auto compute = [&](int buf) {
        bf16x8 af[2], bfr[2];
#pragma unroll
        for (int f = 0; f < 2; ++f) {
            af[f]  = *reinterpret_cast<const bf16x8*>(&sA[buf][(f * 16 + l15) * 32 + kk + pco]);
            bfr[f] = *reinterpret_cast<const bf16x8*>(&sB[buf][(wc + f * 16 + l15) * 32 + kk + pco]);
        }
#pragma unroll
        for (int fr = 0; fr < 2; ++fr)
#pragma unroll
            for (int fc = 0; fc < 2; ++fc)
                acc[fr][fc] = __builtin_amdgcn_mfma_f32_16x16x32_bf16(af[fr], bfr[fc], acc[fr][fc], 0, 0, 0);
    };

    const int NT = Kp >> 5;
    stage(0, 0);
    stage(1, 1);
    int bcur = 0;
    for (int t = 0; t < NT - 1; ++t) {
        asm volatile("s_waitcnt vmcnt(3)" ::: "memory");
        __builtin_amdgcn_s_barrier();
        __builtin_amdgcn_sched_barrier(0);
        if (t + 2 < NT) {
            int bn = bcur + 2; if (bn >= 3) bn -= 3;
            stage(t + 2, bn);
        }
        __builtin_amdgcn_sched_barrier(0);
        compute(bcur);
        bcur = (bcur == 2) ? 0 : bcur + 1;
    }
    asm volatile("s_waitcnt vmcnt(0)" ::: "memory");
    __builtin_amdgcn_s_barrier();
    __builtin_amdgcn_sched_barrier(0);
    compute(bcur);

    const int rowb = r0 + (lane >> 4) * 4;
    const int colb = c0 + wc + l15;
#pragma unroll
    for (int fc = 0; fc < 2; ++fc) {
        int col = colb + fc * 16;
        float bv = (EPI != EPI_NONE) ? bias[col] : 0.f;
#pragma unroll
        for (int fr = 0; fr < 2; ++fr) {
#pragma unroll
            for (int r2 = 0; r2 < 4; ++r2) {
                int row = rowb + fr * 16 + r2;
                if (row >= Rlim) continue;
                float v = acc[fr][fc][r2] + bv;
                if (EPI == EPI_BIAS_RESID) v += resid[(size_t)row * ldc + col];
                if (EPI == EPI_BIAS_GELU)  v = 0.5f * v * (1.f + erff(v * 0.70710678118f));
                if (OF32) ((float*)outp)[(size_t)row * ldc + col] = v;
                else      ((u16*)outp)[(size_t)row * ldc + col] = f2bf(v);
            }
        }
    }
}

// Split-K reduce: out = [gelu](sum_s part[s] + bias). total4 = R*C/4.
template <int GELU, bool OF32>
__global__ void reduce_kernel(const float* __restrict__ part, const float* __restrict__ bias,
                              void* __restrict__ outp, int C, int S, size_t zstride, int total4)
{
    int i = blockIdx.x * 256 + threadIdx.x;
    if (i >= total4) return;
    int cq = C >> 2;
    int rr = i / cq;
    int cc = (i - rr * cq) * 4;
    size_t bidx = (size_t)rr * C + cc;
    float4 s = *reinterpret_cast<const float4*>(&part[bidx]);
    for (int z = 1; z < S; ++z) {
        float4 p = *reinterpret_cast<const float4*>(&part[z * zstride + bidx]);
        s.x += p.x; s.y += p.y; s.z += p.z; s.w += p.w;
    }
    float4 b = *reinterpret_cast<const float4*>(&bias[cc]);
    s.x += b.x; s.y += b.y; s.z += b.z; s.w += b.w;
    if (GELU) {
        s.x = 0.5f * s.x * (1.f + erff(s.x * 0.70710678118f));
        s.y = 0.5f * s.y * (1.f + erff(s.y * 0.70710678118f));
        s.z = 0.5f * s.z * (1.f + erff(s.z * 0.70710678118f));
        s.w = 0.5f * s.w * (1.f + erff(s.w * 0.70710678118f));
    }
    if (OF32) {
        *reinterpret_cast<float4*>(&((float*)outp)[bidx]) = s;
    } else {
        u16 v[4] = { f2bf(s.x), f2bf(s.y), f2bf(s.z), f2bf(s.w) };
        *reinterpret_cast<uint2*>(&((u16*)outp)[bidx]) = *reinterpret_cast<const uint2*>(v);
    }
}

__global__ void rms_kernel(const float* __restrict__ x, const float* __restrict__ w,
                           u16* __restrict__ out, int cols)
{
    const int row = blockIdx.x;
    const int tid = threadIdx.x;
    const float* xr = x + (size_t)row * cols;
    float ss = 0.f;
    for (int c = tid; c < cols; c += 256) { float v = xr[c]; ss += v * v; }
#pragma unroll
    for (int m = 1; m < 64; m <<= 1) ss += __shfl_xor(ss, m);
    __shared__ float wsum[4];
    if ((tid & 63) == 0) wsum[tid >> 6] = ss;
    __syncthreads();
    float tot = wsum[0] + wsum[1] + wsum[2] + wsum[3];
    float rs = rsqrtf(tot / (float)cols + 1e-6f);
    u16* orow = out + (size_t)row * cols;
    for (int c = tid; c < cols; c += 256) orow[c] = f2bf(xr[c] * rs * w[c]);
}

// In-place RoPE on bf16 q,k halves of qkv.
__global__ void rope_kernel(u16* __restrict__ qkv, const float* __restrict__ cosb,
                            const float* __restrict__ sinb)
{
    int idx = blockIdx.x * 256 + threadIdx.x;   // < 1,024,000
    int n   = idx / 640;
    int rem = idx - n * 640;
    int hh  = rem / 40;
    int d   = rem - hh * 40;
    float c0 = cosb[n * 80 + d];
    float s0 = sinb[n * 80 + d];
    float c1 = cosb[n * 80 + d + 40];
    float s1 = sinb[n * 80 + d + 40];
    size_t base = (size_t)n * 3840 + hh * 80;
    float a = bf2f(qkv[base + d]), b = bf2f(qkv[base + d + 40]);
    qkv[base + d]      = f2bf(a * c0 - b * s0);
    qkv[base + d + 40] = f2bf(b * c1 + a * s1);
    base += 1280;
    a = bf2f(qkv[base + d]); b = bf2f(qkv[base + d + 40]);
    qkv[base + d]      = f2bf(a * c0 - b * s0);
    qkv[base + d + 40] = f2bf(b * c1 + a * s1);
}

// silu(gate)*up from fused [1664][6912] buffer -> packed [1664][3456].
__global__ void silu_mul_kernel(const u16* __restrict__ gu, u16* __restrict__ outb)
{
    int idx = blockIdx.x * 256 + threadIdx.x;
    if (idx >= 1664 * 432) return;
    int row = idx / 432, c8 = (idx - row * 432) * 8;
    u16 gv[8], uv[8];
    *reinterpret_cast<uint4*>(gv) = *reinterpret_cast<const uint4*>(&gu[(size_t)row * 6912 + c8]);
    *reinterpret_cast<uint4*>(uv) = *reinterpret_cast<const uint4*>(&gu[(size_t)row * 6912 + 3456 + c8]);
#pragma unroll
    for (int j = 0; j < 8; ++j) {
        float x = bf2f(gv[j]);
        gv[j] = f2bf(x / (1.f + __expf(-x)) * bf2f(uv[j]));
    }
    *reinterpret_cast<uint4*>(&outb[(size_t)row * 3456 + c8]) = *reinterpret_cast<const uint4*>(gv);
}

// Flash attention v2 (r7-proven): double-buffered K/V LDS, reg-staged loads,
// conflict-free packed-u32 V transpose, single barrier per tile.
__global__ __launch_bounds__(256, 2)
void attn_kernel(const u16* __restrict__ qkv, u16* __restrict__ o)
{
    __shared__ __align__(16) u16      Klds[2][64][104];
    __shared__ __align__(16) unsigned Vt32[2][80][36];
    __shared__ __align__(16) u16      Plds[4][16][72];
    const int tid  = threadIdx.x;
    const int lane = tid & 63;
    const int w    = tid >> 6;
    const int l15  = lane & 15;
    const int kk   = (lane >> 4) * 8;
    unsigned lin = blockIdx.y * 25 + blockIdx.x;
    unsigned id2 = (lin & 7) * 50 + (lin >> 3);
    const int hh = (int)(id2 / 25);
    const int qt = (int)(id2 - hh * 25);
    const float scale = 0.11180339887498949f;

    const int koff = 1280 + hh * 80;
    const int voff = 2560 + hh * 80;

    {
        int r  = tid >> 2;
        int cq = 80 + (tid & 3) * 4;
        *reinterpret_cast<uint2*>(&Klds[0][r][cq]) = make_uint2(0u, 0u);
        *reinterpret_cast<uint2*>(&Klds[1][r][cq]) = make_uint2(0u, 0u);
    }

    const int qrow = qt * 64 + w * 16 + l15;
    bf16x8 aq[3];
#pragma unroll
    for (int s = 0; s < 3; ++s) {
        int d = 32 * s + kk;
        union { bf16x8 v; uint4 q; } uu;
        if (d < 80) uu.q = *reinterpret_cast<const uint4*>(&qkv[(size_t)qrow * 3840 + hh * 80 + d]);
        else        uu.q = make_uint4(0u, 0u, 0u, 0u);
        aq[s] = uu.v;
    }

    const int kc0 = tid, kc1 = tid + 256, kc2 = tid + 512;
    const int kr0 = kc0 / 10, k80 = (kc0 - kr0 * 10) * 8;
    const int kr1 = kc1 / 10, k81 = (kc1 - kr1 * 10) * 8;
    const int kr2 = kc2 / 10, k82 = (kc2 - kr2 * 10) * 8;
    const size_t ksrc0 = (size_t)kr0 * 3840 + koff + k80;
    const size_t ksrc1 = (size_t)kr1 * 3840 + koff + k81;
    const size_t ksrc2 = (size_t)kr2 * 3840 + koff + k82;
    const int rpA = tid & 31, gA = tid >> 5;
    const int gB = 8 + (tid >> 5);
    const size_t vsrcA = (size_t)(2 * rpA) * 3840 + voff + gA * 8;
    const size_t vsrcB = (size_t)(2 * rpA) * 3840 + voff + gB * 8;

    uint4 kg0, kg1, kg2, va0, va1, vb0, vb1;
    auto LOADR = [&](int kb) {
        size_t tb = (size_t)kb * 245760;
        kg0 = *reinterpret_cast<const uint4*>(&qkv[tb + ksrc0]);
        kg1 = *reinterpret_cast<const uint4*>(&qkv[tb + ksrc1]);
        if (tid < 128) kg2 = *reinterpret_cast<const uint4*>(&qkv[tb + ksrc2]);
        va0 = *reinterpret_cast<const uint4*>(&qkv[tb + vsrcA]);
        va1 = *reinterpret_cast<const uint4*>(&qkv[tb + vsrcA + 3840]);
        if (tid < 64) {
            vb0 = *reinterpret_cast<const uint4*>(&qkv[tb + vsrcB]);
            vb1 = *reinterpret_cast<const uint4*>(&qkv[tb + vsrcB + 3840]);
        }
    };
    auto STORE = [&](int b) {
        *reinterpret_cast<uint4*>(&Klds[b][kr0][k80]) = kg0;
        *reinterpret_cast<uint4*>(&Klds[b][kr1][k81]) = kg1;
        if (tid < 128) *reinterpret_cast<uint4*>(&Klds[b][kr2][k82]) = kg2;
        union { uint4 q; u16 h[8]; } xa0, xa1;
        xa0.q = va0; xa1.q = va1;
#pragma unroll
        for (int j = 0; j < 8; ++j)
            Vt32[b][gA * 8 + j][rpA] = (unsigned)xa0.h[j] | ((unsigned)xa1.h[j] << 16);
        if (tid < 64) {
            union { uint4 q; u16 h[8]; } xb0, xb1;
            xb0.q = vb0; xb1.q = vb1;
#pragma unroll
            for (int j = 0; j < 8; ++j)
                Vt32[b][gB * 8 + j][rpA] = (unsigned)xb0.h[j] | ((unsigned)xb1.h[j] << 16);
        }
    };

    f32x4 acc_o[5];
#pragma unroll
    for (int fd = 0; fd < 5; ++fd) acc_o[fd] = (f32x4){0.f, 0.f, 0.f, 0.f};
    float m[4], lsum[4];
#pragma unroll
    for (int r2 = 0; r2 < 4; ++r2) { m[r2] = -__builtin_inff(); lsum[r2] = 0.f; }

    LOADR(0);
    STORE(0);
    __syncthreads();
    int cur = 0;

    for (int kb = 0; kb < 25; ++kb) {
        if (kb < 24) LOADR(kb + 1);

        f32x4 sf[4];
#pragma unroll
        for (int fc = 0; fc < 4; ++fc) {
            f32x4 c = (f32x4){0.f, 0.f, 0.f, 0.f};
#pragma unroll
            for (int s = 0; s < 3; ++s)
                c = __builtin_amdgcn_mfma_f32_16x16x32_bf16(
                        aq[s],
                        *reinterpret_cast<const bf16x8*>(&Klds[cur][fc * 16 + l15][32 * s + kk]),
                        c, 0, 0, 0);
            sf[fc] = c * scale;
        }

        float mx[4];
#pragma unroll
        for (int r2 = 0; r2 < 4; ++r2)
            mx[r2] = fmaxf(fmaxf(sf[0][r2], sf[1][r2]), fmaxf(sf[2][r2], sf[3][r2]));
#pragma unroll
        for (int msk = 1; msk <= 8; msk <<= 1)
#pragma unroll
            for (int r2 = 0; r2 < 4; ++r2)
                mx[r2] = fmaxf(mx[r2], __shfl_xor(mx[r2], msk));
        float alpha[4];
#pragma unroll
        for (int r2 = 0; r2 < 4; ++r2) {
            float mn = fmaxf(m[r2], mx[r2]);
            alpha[r2] = __expf(m[r2] - mn);
            m[r2] = mn;
        }
        float psum[4] = {0.f, 0.f, 0.f, 0.f};
#pragma unroll
        for (int fc = 0; fc < 4; ++fc)
#pragma unroll
            for (int r2 = 0; r2 < 4; ++r2) {
                float p = __expf(sf[fc][r2] - m[r2]);
                sf[fc][r2] = p;
                psum[r2] += p;
            }
#pragma unroll
        for (int msk = 1; msk <= 8; msk <<= 1)
#pragma unroll
            for (int r2 = 0; r2 < 4; ++r2) psum[r2] += __shfl_xor(psum[r2], msk);
#pragma unroll
        for (int r2 = 0; r2 < 4; ++r2) lsum[r2] = lsum[r2] * alpha[r2] + psum[r2];
#pragma unroll
        for (int fd = 0; fd < 5; ++fd)
#pragma unroll
            for (int r2 = 0; r2 < 4; ++r2) acc_o[fd][r2] *= alpha[r2];

        const int prow = (lane >> 4) * 4;
#pragma unroll
        for (int fc = 0; fc < 4; ++fc)
#pragma unroll
            for (int r2 = 0; r2 < 4; ++r2)
                Plds[w][prow + r2][fc * 16 + l15] = f2bf(sf[fc][r2]);

        bf16x8 ap[2];
#pragma unroll
        for (int ks = 0; ks < 2; ++ks)
            ap[ks] = *reinterpret_cast<const bf16x8*>(&Plds[w][l15][32 * ks + kk]);
#pragma unroll
        for (int fd = 0; fd < 5; ++fd) {
            const u16* vrow = reinterpret_cast<const u16*>(&Vt32[cur][fd * 16 + l15][0]);
#pragma unroll
            for (int ks = 0; ks < 2; ++ks)
                acc_o[fd] = __builtin_amdgcn_mfma_f32_16x16x32_bf16(
                        ap[ks],
                        *reinterpret_cast<const bf16x8*>(&vrow[32 * ks + kk]),
                        acc_o[fd], 0, 0, 0);
        }

        if (kb < 24) STORE(cur ^ 1);
        __syncthreads();
        cur ^= 1;
    }

    float inv[4];
#pragma unroll
    for (int r2 = 0; r2 < 4; ++r2) inv[r2] = 1.f / lsum[r2];
    const int orow = qt * 64 + w * 16 + (lane >> 4) * 4;
    const int ocol = hh * 80 + l15;
#pragma unroll
    for (int fd = 0; fd < 5; ++fd)
#pragma unroll
        for (int r2 = 0; r2 < 4; ++r2)
            o[(size_t)(orow + r2) * 1280 + ocol + fd * 16] = f2bf(acc_o[fd][r2] * inv[r2]);
}

extern "C" void kernel_launch(void* const* d_in, const int* in_sizes, int n_in,
                              void* d_out, int out_size, void* d_ws, size_t ws_size,
                              hipStream_t stream)
{
    const float* pixel  = (const float*)d_in[0];
    const float* cosb   = (const float*)d_in[1];
    const float* sinb   = (const float*)d_in[2];
    const float* patchw = (const float*)d_in[3];
    const float* n1w    = (const float*)d_in[4];
    const float* qkvw   = (const float*)d_in[5];
    const float* qkvb   = (const float*)d_in[6];
    const float* projw  = (const float*)d_in[7];
    const float* projb  = (const float*)d_in[8];
    const float* n2w    = (const float*)d_in[9];
    const float* gatew  = (const float*)d_in[10];
    const float* gateb  = (const float*)d_in[11];
    const float* upw    = (const float*)d_in[12];
    const float* upb    = (const float*)d_in[13];
    const float* downw  = (const float*)d_in[14];
    const float* downb  = (const float*)d_in[15];
    const float* lnqw   = (const float*)d_in[16];
    const float* m1w    = (const float*)d_in[17];
    const float* m1b    = (const float*)d_in[18];
    const float* m2w    = (const float*)d_in[19];
    const float* m2b    = (const float*)d_in[20];
    float* out = (float*)d_out;

    char* base = (char*)d_ws;
    float* x      = (float*)(base);                       //  1664x1280 f32
    u16*   h      = (u16*)(base + 8519680);               //  1664x1280
    u16*   qbuf   = (u16*)(base + 12779520);              //  1664x3840
    u16*   pix16  = qbuf;                                 //  alias (pre-loop, 1664x1216)
    u16*   gsep   = (u16*)(base + 25559040);              //  1664x3456
    u16*   o      = gsep;                                 //  alias (attn->proj)
    u16*   pw16   = gsep;                                 //  alias (pre-loop, 1280x1216)
    u16*   gu     = (u16*)(base + 37060608);              //  1664x6912
    u16*   t1     = gu;                                   //  alias (post-loop, 512x5120)
    float* guB    = (float*)(base + 60063744);            //  4x6912 f32
    u16*   qkvw16 = (u16*)(base + 60174336);              //  4x3840x1280
    u16*   projw16= (u16*)(base + 99495936);              //  4x1280x1280
    u16*   guw16  = (u16*)(base + 112603136);             //  4x6912x1280
    u16*   downw16= (u16*)(base + 183382016);             //  4x1280x3456 (end 218.8MB)
    u16*   m1w16  = guw16;                                //  alias (post-loop)
    u16*   m2w16  = (u16*)(base + 112603136 + 52428800);  //  alias (post-loop)
    float* part   = (float*)qkvw16;                       //  alias (post-loop, 52.4MB)

    dim3 blk(256);
    auto cvb = [](int Rp, int Cp) { return (Rp * (Cp >> 3) + 255) / 256; };

    cvt_kernel<<<dim3(cvb(1664,1216),1), blk, 0, stream>>>(pixel, pix16, 1600, 1176, 1664, 1216, 0, 0);
    cvt_kernel<<<dim3(cvb(1280,1216),1), blk, 0, stream>>>(patchw, pw16, 1280, 1176, 1280, 1216, 0, 0);
    cvt_kernel<<<dim3(cvb(15360,1280),1), blk, 0, stream>>>(qkvw, qkvw16, 15360, 1280, 15360, 1280, 0, 0);
    cvt_kernel<<<dim3(cvb(5120,1280),1), blk, 0, stream>>>(projw, projw16, 5120, 1280, 5120, 1280, 0, 0);
    cvt_kernel<<<dim3(cvb(3456,1280),4), blk, 0, stream>>>(gatew, guw16, 3420, 1280, 3456, 1280, 4377600LL, 8847360LL);
    cvt_kernel<<<dim3(cvb(3456,1280),4), blk, 0, stream>>>(upw, guw16 + 4423680, 3420, 1280, 3456, 1280, 4377600LL, 8847360LL);
    cvt_kernel<<<dim3(cvb(1280,3456),4), blk, 0, stream>>>(downw, downw16, 1280, 3420, 1280, 3456, 4377600LL, 4423680LL);
    gub_kernel<<<108, blk, 0, stream>>>(gateb, upb, guB);

    gemm32_kernel<EPI_NONE, true><<<dim3(10,52), blk, 0, stream>>>(pix16, pw16, nullptr, nullptr, x, 1216, 1280, 1664);
    for (int i = 0; i < 4; ++i) {
        rms_kernel<<<1600, blk, 0, stream>>>(x, n1w + i*1280, h, 1280);
        gemm32_kernel<EPI_BIAS, false><<<dim3(30,52), blk, 0, stream>>>(h, qkvw16 + (size_t)i*4915200, qkvb + i*3840, nullptr, qbuf, 1280, 3840, 1664);
        rope_kernel<<<4000, blk, 0, stream>>>(qbuf, cosb, sinb);
        attn_kernel<<<dim3(25,16), blk, 0, stream>>>(qbuf, o);
        gemm32_kernel<EPI_BIAS_RESID, true><<<dim3(10,52), blk, 0, stream>>>(o, projw16 + (size_t)i*1638400, projb + i*1280, x, x, 1280, 1280, 1664);
        rms_kernel<<<1600, blk, 0, stream>>>(x, n2w + i*1280, h, 1280);
        gemm32_kernel<EPI_BIAS, false><<<dim3(54,52), blk, 0, stream>>>(h, guw16 + (size_t)i*8847360, guB + i*6912, nullptr, gu, 1280, 6912, 1664);
        silu_mul_kernel<<<2808, blk, 0, stream>>>(gu, gsep);
        gemm32_kernel<EPI_BIAS_RESID, true><<<dim3(10,52), blk, 0, stream>>>(gsep, downw16 + (size_t)i*4423680, downb + i*1280, x, x, 3456, 1280, 1664);
    }
    cvt_kernel<<<dim3(cvb(5120,5120),1), blk, 0, stream>>>(m1w, m1w16, 5120, 5120, 5120, 5120, 0, 0);
    cvt_kernel<<<dim3(cvb(3584,5120),1), blk, 0, stream>>>(m2w, m2w16, 3584, 5120, 3584, 5120, 0, 0);
    rms_kernel<<<1600, blk, 0, stream>>>(x, lnqw, h, 1280);
    gemm16_kernel<EPI_PART, false><<<dim3(40,4,5), blk, 0, stream>>>(h, m1w16, nullptr, nullptr, part, 5120, 5120, 512, 32, 2621440);
    reduce_kernel<1, false><<<2560, blk, 0, stream>>>(part, m1b, t1, 5120, 5, 2621440, 655360);
    gemm16_kernel<EPI_PART, false><<<dim3(28,4,5), blk, 0, stream>>>(t1, m2w16, nullptr, nullptr, part, 5120, 3584, 512, 32, 1835008);
    reduce_kernel<0, true><<<1400, blk, 0, stream>>>(part, m2b, out, 3584, 5, 1835008, 358400);
}

// Round 12
// 1292.536 us; speedup vs baseline: 1.7501x; 1.2087x over previous
//
#include <hip/hip_runtime.h>

// Qwen2.5-VL vision tower forward, MI355X gfx950 — round 11.
// r10 NaN root cause: gemm64 staged only half of each LDS tile (A rows 0-31,
// B rows 0-63). Fixed: 3 gloads/thread (cB0=tid, cB1=tid+256, cA=tid) covers
// 512 B-chunks + 256 A-chunks; vmcnt(3) counted wait. All else = r10 (= r7 +
// gemm64 on qkv, gu on gemm16).

typedef __bf16 bf16x8 __attribute__((ext_vector_type(8)));
typedef float  f32x4  __attribute__((ext_vector_type(4)));
typedef unsigned short u16;

#define DEV __device__ __forceinline__

DEV u16 f2bf(float f) {                       // RNE f32 -> bf16 bits
    union { float f; unsigned u; } v; v.f = f;
    unsigned r = v.u + 0x7FFFu + ((v.u >> 16) & 1u);
    return (u16)(r >> 16);
}
DEV float bf2f(u16 b) {
    union { float f; unsigned u; } v; v.u = ((unsigned)b) << 16; return v.f;
}

DEV void gload16(const u16* g, u16* l) {      // async global->LDS, 16B/lane
    __builtin_amdgcn_global_load_lds(
        (const __attribute__((address_space(1))) unsigned int*)g,
        (__attribute__((address_space(3))) unsigned int*)l, 16, 0, 0);
}

enum { EPI_NONE = 0, EPI_BIAS = 1, EPI_BIAS_RESID = 2, EPI_BIAS_GELU = 3, EPI_PART = 4 };

DEV unsigned xcd_map(unsigned lin, unsigned nwg) {
    unsigned q = nwg >> 3, r = nwg & 7, xc = lin & 7, off = lin >> 3;
    return (xc < r ? xc * (q + 1) : r * (q + 1) + (xc - r) * q) + off;
}

// f32 -> bf16 convert with zero-padding; blockIdx.y = layer.
__global__ void cvt_kernel(const float* __restrict__ src, u16* __restrict__ dst,
                           int Rs, int Cs, int Rp, int Cp,
                           long long sls, long long dls)
{
    const float* s = src + (size_t)blockIdx.y * sls;
    u16* d = dst + (size_t)blockIdx.y * dls;
    int idx = blockIdx.x * 256 + threadIdx.x;
    int cpc = Cp >> 3;
    if (idx >= Rp * cpc) return;
    int row = idx / cpc;
    int c0  = (idx - row * cpc) * 8;
    u16 v[8];
    if (row < Rs && c0 + 8 <= Cs) {
        float4 a = *reinterpret_cast<const float4*>(&s[(size_t)row * Cs + c0]);
        float4 b = *reinterpret_cast<const float4*>(&s[(size_t)row * Cs + c0 + 4]);
        v[0] = f2bf(a.x); v[1] = f2bf(a.y); v[2] = f2bf(a.z); v[3] = f2bf(a.w);
        v[4] = f2bf(b.x); v[5] = f2bf(b.y); v[6] = f2bf(b.z); v[7] = f2bf(b.w);
    } else {
#pragma unroll
        for (int j = 0; j < 8; ++j) {
            int c = c0 + j;
            v[j] = (row < Rs && c < Cs) ? f2bf(s[(size_t)row * Cs + c]) : (u16)0;
        }
    }
    *reinterpret_cast<uint4*>(&d[(size_t)row * Cp + c0]) =
        *reinterpret_cast<const uint4*>(v);
}

// Combined gate|up padded bias: [4][6912] f32.
__global__ void gub_kernel(const float* __restrict__ gb, const float* __restrict__ ub,
                           float* __restrict__ dst)
{
    int i = blockIdx.x * 256 + threadIdx.x;
    if (i >= 4 * 6912) return;
    int l = i / 6912, c = i - l * 6912;
    float v = 0.f;
    if (c < 3456) { if (c < 3420) v = gb[l * 3420 + c]; }
    else { int c2 = c - 3456; if (c2 < 3420) v = ub[l * 3420 + c2]; }
    dst[i] = v;
}

// out(RxC) = A(RxKp) @ B(CxKp)^T, bf16 in. 128x128 tile, BK=32, ring-3 LDS,
// counted vmcnt, chunk-XOR swizzle. Split-K via blockIdx.z (EPI_PART).
template <int EPI, bool OF32>
__global__ __launch_bounds__(256, 3)
void gemm16_kernel(const u16* __restrict__ A, const u16* __restrict__ B,
                   const float* __restrict__ bias, const float* __restrict__ resid,
                   void* __restrict__ outp, int Kp, int ldc, int Rlim,
                   int ktn, size_t zstride)
{
    __shared__ u16 sA[3][4096];
    __shared__ u16 sB[3][4096];
    const int tid  = threadIdx.x;
    const int lane = tid & 63;
    const int w    = tid >> 6;

    const unsigned gy  = gridDim.y;
    const unsigned nwg = gridDim.x * gy;
    const unsigned lin = blockIdx.x + blockIdx.y * gridDim.x;  // HW dispatch order
    const unsigned id2 = xcd_map(lin, nwg);
    const int c0 = (int)(id2 / gy) * 128;
    const int r0 = (int)(id2 - (id2 / gy) * gy) * 128;

    const int wr  = (w >> 1) * 64;
    const int wc  = (w & 1) * 64;
    const int l15 = lane & 15;
    const int kk  = (lane >> 4) * 8;
    const int pco = (((lane >> 4) ^ ((l15 >> 1) & 3)) * 8) - kk;

    const int ca  = w * 128 + lane;
    const int cb  = ca + 64;
    const int sza = ((ca & 3) ^ ((ca >> 3) & 3)) * 8;
    const int szb = ((cb & 3) ^ ((cb >> 3) & 3)) * 8;
    const size_t arow0 = (size_t)(r0 + (ca >> 2)) * Kp + sza;
    const size_t brow0 = (size_t)(c0 + (ca >> 2)) * Kp + sza;
    const size_t arow1 = (size_t)(r0 + (cb >> 2)) * Kp + szb;
    const size_t brow1 = (size_t)(c0 + (cb >> 2)) * Kp + szb;

    f32x4 acc[4][4];
#pragma unroll
    for (int i = 0; i < 4; ++i)
#pragma unroll
        for (int j = 0; j < 4; ++j) acc[i][j] = (f32x4){0.f, 0.f, 0.f, 0.f};

    const int kt0 = blockIdx.z * ktn;
    auto stage = [&](int kt, int buf) {
        int k0 = kt * 32;
        gload16(A + arow0 + k0, &sA[buf][ca * 8]);
        gload16(B + brow0 + k0, &sB[buf][ca * 8]);
        gload16(A + arow1 + k0, &sA[buf][cb * 8]);
        gload16(B + brow1 + k0, &sB[buf][cb * 8]);
    };
    auto compute = [&](int buf) {
        bf16x8 af[4], bfr[4];
#pragma unroll
        for (int f = 0; f < 4; ++f) {
            af[f]  = *reinterpret_cast<const bf16x8*>(&sA[buf][(wr + f * 16 + l15) * 32 + kk + pco]);
            bfr[f] = *reinterpret_cast<const bf16x8*>(&sB[buf][(wc + f * 16 + l15) * 32 + kk + pco]);
        }
#pragma unroll
        for (int fr = 0; fr < 4; ++fr)
#pragma unroll
            for (int fc = 0; fc < 4; ++fc)
                acc[fr][fc] = __builtin_amdgcn_mfma_f32_16x16x32_bf16(af[fr], bfr[fc], acc[fr][fc], 0, 0, 0);
    };

    const int NT = ktn;
    stage(kt0, 0);
    if (NT > 1) stage(kt0 + 1, 1);
    int bcur = 0;
    for (int t = 0; t < NT - 1; ++t) {
        asm volatile("s_waitcnt vmcnt(4)" ::: "memory");
        __builtin_amdgcn_s_barrier();
        __builtin_amdgcn_sched_barrier(0);
        if (t + 2 < NT) {
            int bn = bcur + 2; if (bn >= 3) bn -= 3;
            stage(kt0 + t + 2, bn);
        }
        __builtin_amdgcn_sched_barrier(0);
        compute(bcur);
        bcur = (bcur == 2) ? 0 : bcur + 1;
    }
    asm volatile("s_waitcnt vmcnt(0)" ::: "memory");
    __builtin_amdgcn_s_barrier();
    __builtin_amdgcn_sched_barrier(0);
    compute(bcur);

    const int rowb = r0 + wr + (lane >> 4) * 4;
    const int colb = c0 + wc + l15;
    if (EPI == EPI_PART) {
        float* pp = (float*)outp + (size_t)blockIdx.z * zstride;
#pragma unroll
        for (int fc = 0; fc < 4; ++fc) {
            int col = colb + fc * 16;
#pragma unroll
            for (int fr = 0; fr < 4; ++fr)
#pragma unroll
                for (int r2 = 0; r2 < 4; ++r2)
                    pp[(size_t)(rowb + fr * 16 + r2) * ldc + col] = acc[fr][fc][r2];
        }
        return;
    }
#pragma unroll
    for (int fc = 0; fc < 4; ++fc) {
        int col = colb + fc * 16;
        float bv = (EPI != EPI_NONE) ? bias[col] : 0.f;
#pragma unroll
        for (int fr = 0; fr < 4; ++fr) {
#pragma unroll
            for (int r2 = 0; r2 < 4; ++r2) {
                int row = rowb + fr * 16 + r2;
                if (row >= Rlim) continue;
                float v = acc[fr][fc][r2] + bv;
                if (EPI == EPI_BIAS_RESID) v += resid[(size_t)row * ldc + col];
                if (EPI == EPI_BIAS_GELU)  v = 0.5f * v * (1.f + erff(v * 0.70710678118f));
                if (OF32) ((float*)outp)[(size_t)row * ldc + col] = v;
                else      ((u16*)outp)[(size_t)row * ldc + col] = f2bf(v);
            }
        }
    }
}

// 64x128-tile GEMM: 4 blocks/CU, B-refetch x(M/64). For mid-size B panels.
// Staging: 2 B chunks + 1 A chunk per thread (512 + 256 chunks, full tiles).
template <int EPI, bool OF32>
__global__ __launch_bounds__(256, 4)
void gemm64_kernel(const u16* __restrict__ A, const u16* __restrict__ B,
                   const float* __restrict__ bias, const float* __restrict__ resid,
                   void* __restrict__ outp, int Kp, int ldc, int Rlim)
{
    __shared__ u16 sA[3][2048];
    __shared__ u16 sB[3][4096];
    const int tid  = threadIdx.x;
    const int lane = tid & 63;
    const int w    = tid >> 6;

    const unsigned gy  = gridDim.y;
    const unsigned nwg = gridDim.x * gy;
    const unsigned lin = blockIdx.x + blockIdx.y * gridDim.x;
    const unsigned id2 = xcd_map(lin, nwg);
    const int c0 = (int)(id2 / gy) * 128;
    const int r0 = (int)(id2 - (id2 / gy) * gy) * 64;

    const int wr  = (w >> 1) * 32;
    const int wc  = (w & 1) * 64;
    const int l15 = lane & 15;
    const int kk  = (lane >> 4) * 8;
    const int pco = (((lane >> 4) ^ ((l15 >> 1) & 3)) * 8) - kk;

    const int cB0 = tid, cB1 = tid + 256, cA = tid;
    const size_t bsrc0 = (size_t)(c0 + (cB0 >> 2)) * Kp + ((cB0 & 3) ^ ((cB0 >> 3) & 3)) * 8;
    const size_t bsrc1 = (size_t)(c0 + (cB1 >> 2)) * Kp + ((cB1 & 3) ^ ((cB1 >> 3) & 3)) * 8;
    const size_t asrc  = (size_t)(r0 + (cA  >> 2)) * Kp + ((cA  & 3) ^ ((cA  >> 3) & 3)) * 8;

    f32x4 acc[2][4];
#pragma unroll
    for (int i = 0; i < 2; ++i)
#pragma unroll
        for (int j = 0; j < 4; ++j) acc[i][j] = (f32x4){0.f, 0.f, 0.f, 0.f};

    auto stage = [&](int kt, int buf) {
        int k0 = kt * 32;
        gload16(B + bsrc0 + k0, &sB[buf][cB0 * 8]);
        gload16(B + bsrc1 + k0, &sB[buf][cB1 * 8]);
        gload16(A + asrc  + k0, &sA[buf][cA * 8]);
    };
    auto compute = [&](int buf) {
        bf16x8 af[2], bfr[4];
#pragma unroll
        for (int f = 0; f < 2; ++f)
            af[f]  = *reinterpret_cast<const bf16x8*>(&sA[buf][(wr + f * 16 + l15) * 32 + kk + pco]);
#pragma unroll
        for (int f = 0; f < 4; ++f)
            bfr[f] = *reinterpret_cast<const bf16x8*>(&sB[buf][(wc + f * 16 + l15) * 32 + kk + pco]);
#pragma unroll
        for (int fr = 0; fr < 2; ++fr)
#pragma unroll
            for (int fc = 0; fc < 4; ++fc)
                acc[fr][fc] = __builtin_amdgcn_mfma_f32_16x16x32_bf16(af[fr], bfr[fc], acc[fr][fc], 0, 0, 0);
    };

    const int NT = Kp >> 5;
    stage(0, 0);
    stage(1, 1);
    int bcur = 0;
    for (int t = 0; t < NT - 1; ++t) {
        asm volatile("s_waitcnt vmcnt(3)" ::: "memory");
        __builtin_amdgcn_s_barrier();
        __builtin_amdgcn_sched_barrier(0);
        if (t + 2 < NT) {
            int bn = bcur + 2; if (bn >= 3) bn -= 3;
            stage(t + 2, bn);
        }
        __builtin_amdgcn_sched_barrier(0);
        compute(bcur);
        bcur = (bcur == 2) ? 0 : bcur + 1;
    }
    asm volatile("s_waitcnt vmcnt(0)" ::: "memory");
    __builtin_amdgcn_s_barrier();
    __builtin_amdgcn_sched_barrier(0);
    compute(bcur);

    const int rowb = r0 + wr + (lane >> 4) * 4;
    const int colb = c0 + wc + l15;
#pragma unroll
    for (int fc = 0; fc < 4; ++fc) {
        int col = colb + fc * 16;
        float bv = (EPI != EPI_NONE) ? bias[col] : 0.f;
#pragma unroll
        for (int fr = 0; fr < 2; ++fr) {
#pragma unroll
            for (int r2 = 0; r2 < 4; ++r2) {
                int row = rowb + fr * 16 + r2;
                if (row >= Rlim) continue;
                float v = acc[fr][fc][r2] + bv;
                if (EPI == EPI_BIAS_RESID) v += resid[(size_t)row * ldc + col];
                if (EPI == EPI_BIAS_GELU)  v = 0.5f * v * (1.f + erff(v * 0.70710678118f));
                if (OF32) ((float*)outp)[(size_t)row * ldc + col] = v;
                else      ((u16*)outp)[(size_t)row * ldc + col] = f2bf(v);
            }
        }
    }
}

// 32x128-tile GEMM for small-B residency-bound shapes (patch, proj, down).
template <int EPI, bool OF32>
__global__ __launch_bounds__(256, 4)
void gemm32_kernel(const u16* __restrict__ A, const u16* __restrict__ B,
                   const float* __restrict__ bias, const float* __restrict__ resid,
                   void* __restrict__ outp, int Kp, int ldc, int Rlim)
{
    __shared__ u16 sA[3][1024];
    __shared__ u16 sB[3][4096];
    const int tid  = threadIdx.x;
    const int lane = tid & 63;
    const int w    = tid >> 6;

    const unsigned gy  = gridDim.y;
    const unsigned nwg = gridDim.x * gy;
    const unsigned lin = blockIdx.x + blockIdx.y * gridDim.x;
    const unsigned id2 = xcd_map(lin, nwg);
    const int c0 = (int)(id2 / gy) * 128;
    const int r0 = (int)(id2 - (id2 / gy) * gy) * 32;

    const int wc  = w * 32;
    const int l15 = lane & 15;
    const int kk  = (lane >> 4) * 8;
    const int pco = (((lane >> 4) ^ ((l15 >> 1) & 3)) * 8) - kk;

    const int cB0 = tid, cB1 = tid + 256, cA = tid & 127;
    const size_t bsrc0 = (size_t)(c0 + (cB0 >> 2)) * Kp + ((cB0 & 3) ^ ((cB0 >> 3) & 3)) * 8;
    const size_t bsrc1 = (size_t)(c0 + (cB1 >> 2)) * Kp + ((cB1 & 3) ^ ((cB1 >> 3) & 3)) * 8;
    const size_t asrc  = (size_t)(r0 + (cA  >> 2)) * Kp + ((cA  & 3) ^ ((cA  >> 3) & 3)) * 8;

    f32x4 acc[2][2];
#pragma unroll
    for (int i = 0; i < 2; ++i)
#pragma unroll
        for (int j = 0; j < 2; ++j) acc[i][j] = (f32x4){0.f, 0.f, 0.f, 0.f};

    auto stage = [&](int kt, int buf) {
        int k0 = kt * 32;
        gload16(B + bsrc0 + k0, &sB[buf][cB0 * 8]);
        gload16(B + bsrc1 + k0, &sB[buf][cB1 * 8]);
        gload16(A + asrc  + k0, &sA[buf][cA * 8]);
    };
    auto compute = [&](int buf) {
        bf16x8 af[2], bfr[2];
#pragma unroll
        for (int f = 0; f < 2; ++f) {
            af[f]  = *reinterpret_cast<const bf16x8*>(&sA[buf][(f * 16 + l15) * 32 + kk + pco]);
            bfr[f] = *reinterpret_cast<const bf16x8*>(&sB[buf][(wc + f * 16 + l15) * 32 + kk + pco]);
        }
#pragma unroll
        for (int fr = 0; fr < 2; ++fr)
#pragma unroll
            for (int fc = 0; fc < 2; ++fc)
                acc[fr][fc] = __builtin_amdgcn_mfma_f32_16x16x32_bf16(af[fr], bfr[fc], acc[fr][fc], 0, 0, 0);
    };

    const int NT = Kp >> 5;
    stage(0, 0);
    stage(1, 1);
    int bcur = 0;
    for (int t = 0; t < NT - 1; ++t) {
        asm volatile("s_waitcnt vmcnt(3)" ::: "memory");
        __builtin_amdgcn_s_barrier();
        __builtin_amdgcn_sched_barrier(0);
        if (t + 2 < NT) {
            int bn = bcur + 2; if (bn >= 3) bn -= 3;
            stage(t + 2, bn);
        }
        __builtin_amdgcn_sched_barrier(0);
        compute(bcur);
        bcur = (bcur == 2) ? 0 : bcur + 1;
    }
    asm volatile("s_waitcnt vmcnt(0)" ::: "memory");
    __builtin_amdgcn_s_barrier();
    __builtin_amdgcn_sched_barrier(0);
    compute(bcur);

    const int rowb = r0 + (lane >> 4) * 4;
    const int colb = c0 + wc + l15;
#pragma unroll
    for (int fc = 0; fc < 2; ++fc) {
        int col = colb + fc * 16;
        float bv = (EPI != EPI_NONE) ? bias[col] : 0.f;
#pragma unroll
        for (int fr = 0; fr < 2; ++fr) {
#pragma unroll
            for (int r2 = 0; r2 < 4; ++r2) {
                int row = rowb + fr * 16 + r2;
                if (row >= Rlim) continue;
                float v = acc[fr][fc][r2] + bv;
                if (EPI == EPI_BIAS_RESID) v += resid[(size_t)row * ldc + col];
                if (EPI == EPI_BIAS_GELU)  v = 0.5f * v * (1.f + erff(v * 0.70710678118f));
                if (OF32) ((float*)outp)[(size_t)row * ldc + col] = v;
                else      ((u16*)outp)[(size_t)row * ldc + col] = f2bf(v);
            }
        }
    }
}

// Split-K reduce: out = [gelu](sum_s part[s] + bias). total4 = R*C/4.
template <int GELU, bool OF32>
__global__ void reduce_kernel(const float* __restrict__ part, const float* __restrict__ bias,
                              void* __restrict__ outp, int C, int S, size_t zstride, int total4)
{
    int i = blockIdx.x * 256 + threadIdx.x;
    if (i >= total4) return;
    int cq = C >> 2;
    int rr = i / cq;
    int cc = (i - rr * cq) * 4;
    size_t bidx = (size_t)rr * C + cc;
    float4 s = *reinterpret_cast<const float4*>(&part[bidx]);
    for (int z = 1; z < S; ++z) {
        float4 p = *reinterpret_cast<const float4*>(&part[z * zstride + bidx]);
        s.x += p.x; s.y += p.y; s.z += p.z; s.w += p.w;
    }
    float4 b = *reinterpret_cast<const float4*>(&bias[cc]);
    s.x += b.x; s.y += b.y; s.z += b.z; s.w += b.w;
    if (GELU) {
        s.x = 0.5f * s.x * (1.f + erff(s.x * 0.70710678118f));
        s.y = 0.5f * s.y * (1.f + erff(s.y * 0.70710678118f));
        s.z = 0.5f * s.z * (1.f + erff(s.z * 0.70710678118f));
        s.w = 0.5f * s.w * (1.f + erff(s.w * 0.70710678118f));
    }
    if (OF32) {
        *reinterpret_cast<float4*>(&((float*)outp)[bidx]) = s;
    } else {
        u16 v[4] = { f2bf(s.x), f2bf(s.y), f2bf(s.z), f2bf(s.w) };
        *reinterpret_cast<uint2*>(&((u16*)outp)[bidx]) = *reinterpret_cast<const uint2*>(v);
    }
}

__global__ void rms_kernel(const float* __restrict__ x, const float* __restrict__ w,
                           u16* __restrict__ out, int cols)
{
    const int row = blockIdx.x;
    const int tid = threadIdx.x;
    const float* xr = x + (size_t)row * cols;
    float ss = 0.f;
    for (int c = tid; c < cols; c += 256) { float v = xr[c]; ss += v * v; }
#pragma unroll
    for (int m = 1; m < 64; m <<= 1) ss += __shfl_xor(ss, m);
    __shared__ float wsum[4];
    if ((tid & 63) == 0) wsum[tid >> 6] = ss;
    __syncthreads();
    float tot = wsum[0] + wsum[1] + wsum[2] + wsum[3];
    float rs = rsqrtf(tot / (float)cols + 1e-6f);
    u16* orow = out + (size_t)row * cols;
    for (int c = tid; c < cols; c += 256) orow[c] = f2bf(xr[c] * rs * w[c]);
}

// In-place RoPE on bf16 q,k halves of qkv.
__global__ void rope_kernel(u16* __restrict__ qkv, const float* __restrict__ cosb,
                            const float* __restrict__ sinb)
{
    int idx = blockIdx.x * 256 + threadIdx.x;   // < 1,024,000
    int n   = idx / 640;
    int rem = idx - n * 640;
    int hh  = rem / 40;
    int d   = rem - hh * 40;
    float c0 = cosb[n * 80 + d];
    float s0 = sinb[n * 80 + d];
    float c1 = cosb[n * 80 + d + 40];
    float s1 = sinb[n * 80 + d + 40];
    size_t base = (size_t)n * 3840 + hh * 80;
    float a = bf2f(qkv[base + d]), b = bf2f(qkv[base + d + 40]);
    qkv[base + d]      = f2bf(a * c0 - b * s0);
    qkv[base + d + 40] = f2bf(b * c1 + a * s1);
    base += 1280;
    a = bf2f(qkv[base + d]); b = bf2f(qkv[base + d + 40]);
    qkv[base + d]      = f2bf(a * c0 - b * s0);
    qkv[base + d + 40] = f2bf(b * c1 + a * s1);
}

// silu(gate)*up from fused [1664][6912] buffer -> packed [1664][3456].
__global__ void silu_mul_kernel(const u16* __restrict__ gu, u16* __restrict__ outb)
{
    int idx = blockIdx.x * 256 + threadIdx.x;
    if (idx >= 1664 * 432) return;
    int row = idx / 432, c8 = (idx - row * 432) * 8;
    u16 gv[8], uv[8];
    *reinterpret_cast<uint4*>(gv) = *reinterpret_cast<const uint4*>(&gu[(size_t)row * 6912 + c8]);
    *reinterpret_cast<uint4*>(uv) = *reinterpret_cast<const uint4*>(&gu[(size_t)row * 6912 + 3456 + c8]);
#pragma unroll
    for (int j = 0; j < 8; ++j) {
        float x = bf2f(gv[j]);
        gv[j] = f2bf(x / (1.f + __expf(-x)) * bf2f(uv[j]));
    }
    *reinterpret_cast<uint4*>(&outb[(size_t)row * 3456 + c8]) = *reinterpret_cast<const uint4*>(gv);
}

// Flash attention v2 (r7-proven): double-buffered K/V LDS, reg-staged loads,
// conflict-free packed-u32 V transpose, single barrier per tile.
__global__ __launch_bounds__(256, 2)
void attn_kernel(const u16* __restrict__ qkv, u16* __restrict__ o)
{
    __shared__ __align__(16) u16      Klds[2][64][104];
    __shared__ __align__(16) unsigned Vt32[2][80][36];
    __shared__ __align__(16) u16      Plds[4][16][72];
    const int tid  = threadIdx.x;
    const int lane = tid & 63;
    const int w    = tid >> 6;
    const int l15  = lane & 15;
    const int kk   = (lane >> 4) * 8;
    unsigned lin = blockIdx.y * 25 + blockIdx.x;
    unsigned id2 = (lin & 7) * 50 + (lin >> 3);
    const int hh = (int)(id2 / 25);
    const int qt = (int)(id2 - hh * 25);
    const float scale = 0.11180339887498949f;

    const int koff = 1280 + hh * 80;
    const int voff = 2560 + hh * 80;

    {
        int r  = tid >> 2;
        int cq = 80 + (tid & 3) * 4;
        *reinterpret_cast<uint2*>(&Klds[0][r][cq]) = make_uint2(0u, 0u);
        *reinterpret_cast<uint2*>(&Klds[1][r][cq]) = make_uint2(0u, 0u);
    }

    const int qrow = qt * 64 + w * 16 + l15;
    bf16x8 aq[3];
#pragma unroll
    for (int s = 0; s < 3; ++s) {
        int d = 32 * s + kk;
        union { bf16x8 v; uint4 q; } uu;
        if (d < 80) uu.q = *reinterpret_cast<const uint4*>(&qkv[(size_t)qrow * 3840 + hh * 80 + d]);
        else        uu.q = make_uint4(0u, 0u, 0u, 0u);
        aq[s] = uu.v;
    }

    const int kc0 = tid, kc1 = tid + 256, kc2 = tid + 512;
    const int kr0 = kc0 / 10, k80 = (kc0 - kr0 * 10) * 8;
    const int kr1 = kc1 / 10, k81 = (kc1 - kr1 * 10) * 8;
    const int kr2 = kc2 / 10, k82 = (kc2 - kr2 * 10) * 8;
    const size_t ksrc0 = (size_t)kr0 * 3840 + koff + k80;
    const size_t ksrc1 = (size_t)kr1 * 3840 + koff + k81;
    const size_t ksrc2 = (size_t)kr2 * 3840 + koff + k82;
    const int rpA = tid & 31, gA = tid >> 5;
    const int gB = 8 + (tid >> 5);
    const size_t vsrcA = (size_t)(2 * rpA) * 3840 + voff + gA * 8;
    const size_t vsrcB = (size_t)(2 * rpA) * 3840 + voff + gB * 8;

    uint4 kg0, kg1, kg2, va0, va1, vb0, vb1;
    auto LOADR = [&](int kb) {
        size_t tb = (size_t)kb * 245760;
        kg0 = *reinterpret_cast<const uint4*>(&qkv[tb + ksrc0]);
        kg1 = *reinterpret_cast<const uint4*>(&qkv[tb + ksrc1]);
        if (tid < 128) kg2 = *reinterpret_cast<const uint4*>(&qkv[tb + ksrc2]);
        va0 = *reinterpret_cast<const uint4*>(&qkv[tb + vsrcA]);
        va1 = *reinterpret_cast<const uint4*>(&qkv[tb + vsrcA + 3840]);
        if (tid < 64) {
            vb0 = *reinterpret_cast<const uint4*>(&qkv[tb + vsrcB]);
            vb1 = *reinterpret_cast<const uint4*>(&qkv[tb + vsrcB + 3840]);
        }
    };
    auto STORE = [&](int b) {
        *reinterpret_cast<uint4*>(&Klds[b][kr0][k80]) = kg0;
        *reinterpret_cast<uint4*>(&Klds[b][kr1][k81]) = kg1;
        if (tid < 128) *reinterpret_cast<uint4*>(&Klds[b][kr2][k82]) = kg2;
        union { uint4 q; u16 h[8]; } xa0, xa1;
        xa0.q = va0; xa1.q = va1;
#pragma unroll
        for (int j = 0; j < 8; ++j)
            Vt32[b][gA * 8 + j][rpA] = (unsigned)xa0.h[j] | ((unsigned)xa1.h[j] << 16);
        if (tid < 64) {
            union { uint4 q; u16 h[8]; } xb0, xb1;
            xb0.q = vb0; xb1.q = vb1;
#pragma unroll
            for (int j = 0; j < 8; ++j)
                Vt32[b][gB * 8 + j][rpA] = (unsigned)xb0.h[j] | ((unsigned)xb1.h[j] << 16);
        }
    };

    f32x4 acc_o[5];
#pragma unroll
    for (int fd = 0; fd < 5; ++fd) acc_o[fd] = (f32x4){0.f, 0.f, 0.f, 0.f};
    float m[4], lsum[4];
#pragma unroll
    for (int r2 = 0; r2 < 4; ++r2) { m[r2] = -__builtin_inff(); lsum[r2] = 0.f; }

    LOADR(0);
    STORE(0);
    __syncthreads();
    int cur = 0;

    for (int kb = 0; kb < 25; ++kb) {
        if (kb < 24) LOADR(kb + 1);

        f32x4 sf[4];
#pragma unroll
        for (int fc = 0; fc < 4; ++fc) {
            f32x4 c = (f32x4){0.f, 0.f, 0.f, 0.f};
#pragma unroll
            for (int s = 0; s < 3; ++s)
                c = __builtin_amdgcn_mfma_f32_16x16x32_bf16(
                        aq[s],
                        *reinterpret_cast<const bf16x8*>(&Klds[cur][fc * 16 + l15][32 * s + kk]),
                        c, 0, 0, 0);
            sf[fc] = c * scale;
        }

        float mx[4];
#pragma unroll
        for (int r2 = 0; r2 < 4; ++r2)
            mx[r2] = fmaxf(fmaxf(sf[0][r2], sf[1][r2]), fmaxf(sf[2][r2], sf[3][r2]));
#pragma unroll
        for (int msk = 1; msk <= 8; msk <<= 1)
#pragma unroll
            for (int r2 = 0; r2 < 4; ++r2)
                mx[r2] = fmaxf(mx[r2], __shfl_xor(mx[r2], msk));
        float alpha[4];
#pragma unroll
        for (int r2 = 0; r2 < 4; ++r2) {
            float mn = fmaxf(m[r2], mx[r2]);
            alpha[r2] = __expf(m[r2] - mn);
            m[r2] = mn;
        }
        float psum[4] = {0.f, 0.f, 0.f, 0.f};
#pragma unroll
        for (int fc = 0; fc < 4; ++fc)
#pragma unroll
            for (int r2 = 0; r2 < 4; ++r2) {
                float p = __expf(sf[fc][r2] - m[r2]);
                sf[fc][r2] = p;
                psum[r2] += p;
            }
#pragma unroll
        for (int msk = 1; msk <= 8; msk <<= 1)
#pragma unroll
            for (int r2 = 0; r2 < 4; ++r2) psum[r2] += __shfl_xor(psum[r2], msk);
#pragma unroll
        for (int r2 = 0; r2 < 4; ++r2) lsum[r2] = lsum[r2] * alpha[r2] + psum[r2];
#pragma unroll
        for (int fd = 0; fd < 5; ++fd)
#pragma unroll
            for (int r2 = 0; r2 < 4; ++r2) acc_o[fd][r2] *= alpha[r2];

        const int prow = (lane >> 4) * 4;
#pragma unroll
        for (int fc = 0; fc < 4; ++fc)
#pragma unroll
            for (int r2 = 0; r2 < 4; ++r2)
                Plds[w][prow + r2][fc * 16 + l15] = f2bf(sf[fc][r2]);

        bf16x8 ap[2];
#pragma unroll
        for (int ks = 0; ks < 2; ++ks)
            ap[ks] = *reinterpret_cast<const bf16x8*>(&Plds[w][l15][32 * ks + kk]);
#pragma unroll
        for (int fd = 0; fd < 5; ++fd) {
            const u16* vrow = reinterpret_cast<const u16*>(&Vt32[cur][fd * 16 + l15][0]);
#pragma unroll
            for (int ks = 0; ks < 2; ++ks)
                acc_o[fd] = __builtin_amdgcn_mfma_f32_16x16x32_bf16(
                        ap[ks],
                        *reinterpret_cast<const bf16x8*>(&vrow[32 * ks + kk]),
                        acc_o[fd], 0, 0, 0);
        }

        if (kb < 24) STORE(cur ^ 1);
        __syncthreads();
        cur ^= 1;
    }

    float inv[4];
#pragma unroll
    for (int r2 = 0; r2 < 4; ++r2) inv[r2] = 1.f / lsum[r2];
    const int orow = qt * 64 + w * 16 + (lane >> 4) * 4;
    const int ocol = hh * 80 + l15;
#pragma unroll
    for (int fd = 0; fd < 5; ++fd)
#pragma unroll
        for (int r2 = 0; r2 < 4; ++r2)
            o[(size_t)(orow + r2) * 1280 + ocol + fd * 16] = f2bf(acc_o[fd][r2] * inv[r2]);
}

extern "C" void kernel_launch(void* const* d_in, const int* in_sizes, int n_in,
                              void* d_out, int out_size, void* d_ws, size_t ws_size,
                              hipStream_t stream)
{
    const float* pixel  = (const float*)d_in[0];
    const float* cosb   = (const float*)d_in[1];
    const float* sinb   = (const float*)d_in[2];
    const float* patchw = (const float*)d_in[3];
    const float* n1w    = (const float*)d_in[4];
    const float* qkvw   = (const float*)d_in[5];
    const float* qkvb   = (const float*)d_in[6];
    const float* projw  = (const float*)d_in[7];
    const float* projb  = (const float*)d_in[8];
    const float* n2w    = (const float*)d_in[9];
    const float* gatew  = (const float*)d_in[10];
    const float* gateb  = (const float*)d_in[11];
    const float* upw    = (const float*)d_in[12];
    const float* upb    = (const float*)d_in[13];
    const float* downw  = (const float*)d_in[14];
    const float* downb  = (const float*)d_in[15];
    const float* lnqw   = (const float*)d_in[16];
    const float* m1w    = (const float*)d_in[17];
    const float* m1b    = (const float*)d_in[18];
    const float* m2w    = (const float*)d_in[19];
    const float* m2b    = (const float*)d_in[20];
    float* out = (float*)d_out;

    char* base = (char*)d_ws;
    float* x      = (float*)(base);                       //  1664x1280 f32
    u16*   h      = (u16*)(base + 8519680);               //  1664x1280
    u16*   qbuf   = (u16*)(base + 12779520);              //  1664x3840
    u16*   pix16  = qbuf;                                 //  alias (pre-loop, 1664x1216)
    u16*   gsep   = (u16*)(base + 25559040);              //  1664x3456
    u16*   o      = gsep;                                 //  alias (attn->proj)
    u16*   pw16   = gsep;                                 //  alias (pre-loop, 1280x1216)
    u16*   gu     = (u16*)(base + 37060608);              //  1664x6912
    u16*   t1     = gu;                                   //  alias (post-loop, 512x5120)
    float* guB    = (float*)(base + 60063744);            //  4x6912 f32
    u16*   qkvw16 = (u16*)(base + 60174336);              //  4x3840x1280
    u16*   projw16= (u16*)(base + 99495936);              //  4x1280x1280
    u16*   guw16  = (u16*)(base + 112603136);             //  4x6912x1280
    u16*   downw16= (u16*)(base + 183382016);             //  4x1280x3456 (end 218.8MB)
    u16*   m1w16  = guw16;                                //  alias (post-loop)
    u16*   m2w16  = (u16*)(base + 112603136 + 52428800);  //  alias (post-loop)
    float* part   = (float*)qkvw16;                       //  alias (post-loop, 52.4MB)

    dim3 blk(256);
    auto cvb = [](int Rp, int Cp) { return (Rp * (Cp >> 3) + 255) / 256; };

    cvt_kernel<<<dim3(cvb(1664,1216),1), blk, 0, stream>>>(pixel, pix16, 1600, 1176, 1664, 1216, 0, 0);
    cvt_kernel<<<dim3(cvb(1280,1216),1), blk, 0, stream>>>(patchw, pw16, 1280, 1176, 1280, 1216, 0, 0);
    cvt_kernel<<<dim3(cvb(15360,1280),1), blk, 0, stream>>>(qkvw, qkvw16, 15360, 1280, 15360, 1280, 0, 0);
    cvt_kernel<<<dim3(cvb(5120,1280),1), blk, 0, stream>>>(projw, projw16, 5120, 1280, 5120, 1280, 0, 0);
    cvt_kernel<<<dim3(cvb(3456,1280),4), blk, 0, stream>>>(gatew, guw16, 3420, 1280, 3456, 1280, 4377600LL, 8847360LL);
    cvt_kernel<<<dim3(cvb(3456,1280),4), blk, 0, stream>>>(upw, guw16 + 4423680, 3420, 1280, 3456, 1280, 4377600LL, 8847360LL);
    cvt_kernel<<<dim3(cvb(1280,3456),4), blk, 0, stream>>>(downw, downw16, 1280, 3420, 1280, 3456, 4377600LL, 4423680LL);
    gub_kernel<<<108, blk, 0, stream>>>(gateb, upb, guB);

    gemm32_kernel<EPI_NONE, true><<<dim3(10,52), blk, 0, stream>>>(pix16, pw16, nullptr, nullptr, x, 1216, 1280, 1664);
    for (int i = 0; i < 4; ++i) {
        rms_kernel<<<1600, blk, 0, stream>>>(x, n1w + i*1280, h, 1280);
        gemm64_kernel<EPI_BIAS, false><<<dim3(30,26), blk, 0, stream>>>(h, qkvw16 + (size_t)i*4915200, qkvb + i*3840, nullptr, qbuf, 1280, 3840, 1664);
        rope_kernel<<<4000, blk, 0, stream>>>(qbuf, cosb, sinb);
        attn_kernel<<<dim3(25,16), blk, 0, stream>>>(qbuf, o);
        gemm32_kernel<EPI_BIAS_RESID, true><<<dim3(10,52), blk, 0, stream>>>(o, projw16 + (size_t)i*1638400, projb + i*1280, x, x, 1280, 1280, 1664);
        rms_kernel<<<1600, blk, 0, stream>>>(x, n2w + i*1280, h, 1280);
        gemm16_kernel<EPI_BIAS, false><<<dim3(54,13), blk, 0, stream>>>(h, guw16 + (size_t)i*8847360, guB + i*6912, nullptr, gu, 1280, 6912, 1664, 40, 0);
        silu_mul_kernel<<<2808, blk, 0, stream>>>(gu, gsep);
        gemm32_kernel<EPI_BIAS_RESID, true><<<dim3(10,52), blk, 0, stream>>>(gsep, downw16 + (size_t)i*4423680, downb + i*1280, x, x, 3456, 1280, 1664);
    }
    cvt_kernel<<<dim3(cvb(5120,5120),1), blk, 0, stream>>>(m1w, m1w16, 5120, 5120, 5120, 5120, 0, 0);
    cvt_kernel<<<dim3(cvb(3584,5120),1), blk, 0, stream>>>(m2w, m2w16, 3584, 5120, 3584, 5120, 0, 0);
    rms_kernel<<<1600, blk, 0, stream>>>(x, lnqw, h, 1280);
    gemm16_kernel<EPI_PART, false><<<dim3(40,4,5), blk, 0, stream>>>(h, m1w16, nullptr, nullptr, part, 5120, 5120, 512, 32, 2621440);
    reduce_kernel<1, false><<<2560, blk, 0, stream>>>(part, m1b, t1, 5120, 5, 2621440, 655360);
    gemm16_kernel<EPI_PART, false><<<dim3(28,4,5), blk, 0, stream>>>(t1, m2w16, nullptr, nullptr, part, 5120, 3584, 512, 32, 1835008);
    reduce_kernel<0, true><<<1400, blk, 0, stream>>>(part, m2b, out, 3584, 5, 1835008, 358400);
}